// Round 2
// baseline (2028.008 us; speedup 1.0000x reference)
//
#include <hip/hip_runtime.h>

#define B_SZ   32
#define S_LEN  512
#define HID    768
#define DH     384
#define G4     1536
#define NPOS   16384   // B_SZ * S_LEN
#define EPS_C  0.5f
#define NCH    24576   // B_SZ * HID channels
#define CHK    64      // gate-scan chunk length
#define NCHK   8       // S_LEN / CHK

typedef _Float16 h2 __attribute__((ext_vector_type(2)));
typedef short bf16x8 __attribute__((ext_vector_type(8)));
typedef float f32x4 __attribute__((ext_vector_type(4)));

static __device__ __forceinline__ float sigm(float x) { return 1.0f / (1.0f + __expf(-x)); }
static __device__ __forceinline__ float tanh_fast(float x) {
    return 1.0f - 2.0f / (__expf(2.0f * x) + 1.0f);
}

static __device__ __forceinline__ unsigned short f2bf(float f) {
    union { float f; unsigned u; } v; v.f = f;
    unsigned r = v.u + 0x7FFF + ((v.u >> 16) & 1);
    return (unsigned short)(r >> 16);
}
static __device__ __forceinline__ float bf2f(unsigned short u) {
    union { unsigned u; float f; } v; v.u = ((unsigned)u) << 16; return v.f;
}

static __device__ __forceinline__ float wred(float v) {
#pragma unroll
    for (int off = 32; off > 0; off >>= 1) v += __shfl_down(v, off, 64);
    return v;
}

static __device__ __forceinline__ float dot2acc(h2 a, h2 b, float c) {
#if __has_builtin(__builtin_amdgcn_fdot2)
    return __builtin_amdgcn_fdot2(a, b, c, false);
#else
    return c + (float)a.x * (float)b.x + (float)a.y * (float)b.y;
#endif
}

// ---------------------------------------------------------------------------
// K0a: pack w_hh fp32 [1536,384] -> fp16-pair u32 [2][1536][192]  (scan wts)
// ---------------------------------------------------------------------------
__global__ void wprep(const float* __restrict__ wf, const float* __restrict__ wb,
                      unsigned* __restrict__ wpk) {
    int gid = blockIdx.x * 256 + threadIdx.x;       // < 589824
    int d = (gid >= 294912) ? 1 : 0;
    int j = gid - d * 294912;
    const float* src = d ? wb : wf;
    _Float16 a = (_Float16)src[2 * j];
    _Float16 b = (_Float16)src[2 * j + 1];
    unsigned pa = __builtin_bit_cast(unsigned short, a);
    unsigned pb = __builtin_bit_cast(unsigned short, b);
    wpk[(size_t)d * 294912 + j] = pa | (pb << 16);
}

// ---------------------------------------------------------------------------
// K0b: fp32 -> bf16 cast (n multiple of 4)
// ---------------------------------------------------------------------------
__global__ __launch_bounds__(256) void cast_bf16(
    const float* __restrict__ src, unsigned short* __restrict__ dst, int n4) {
    int i = blockIdx.x * 256 + threadIdx.x;
    if (i >= n4) return;
    float4 v = *(const float4*)(src + (size_t)i * 4);
    ushort4 o;
    o.x = f2bf(v.x); o.y = f2bf(v.y); o.z = f2bf(v.z); o.w = f2bf(v.w);
    *(ushort4*)(dst + (size_t)i * 4) = o;
}

// ---------------------------------------------------------------------------
// K0c: W_gate [K=768][N=768] -> bf16 transposed [N][K] (read-coalesced)
// ---------------------------------------------------------------------------
__global__ __launch_bounds__(256) void wgt_prep(
    const float* __restrict__ Wg, unsigned short* __restrict__ Wgt) {
    int i = blockIdx.x * 256 + threadIdx.x;          // < 589824
    int k = i / 768, n = i - k * 768;
    Wgt[(size_t)n * 768 + k] = f2bf(Wg[i]);
}

// ---------------------------------------------------------------------------
// K1: z_t head. One wave / position. NO atomics: per-block partial sums.
// ---------------------------------------------------------------------------
__global__ __launch_bounds__(256) void zt_kernel(
    const float* __restrict__ x, const int* __restrict__ amask,
    const int* __restrict__ labn, const float* __restrict__ Wfc,
    const float* __restrict__ bfc, const float* __restrict__ Wtr,
    float* __restrict__ alpha, float* __restrict__ zsp,
    float* __restrict__ p0, float* __restrict__ p2) {
    const int gid  = blockIdx.x * blockDim.x + threadIdx.x;
    const int pos  = gid >> 6, lane = gid & 63, wv = threadIdx.x >> 6;
    __shared__ float r0[4], r2[4];
    const float* xp = x + (size_t)pos * HID;
    float a0 = 0.f, a1 = 0.f, a2 = 0.f;
#pragma unroll
    for (int j = 0; j < 12; ++j) {
        int k = lane + (j << 6);
        float xv = xp[k];
        a0 += xv * Wfc[k * 3 + 0];
        a1 += xv * Wfc[k * 3 + 1];
        a2 += xv * Wfc[k * 3 + 2];
    }
    a0 = wred(a0); a1 = wred(a1); a2 = wred(a2);
    if (lane == 0) {
        float z0 = a0 + bfc[0], z1 = a1 + bfc[1], z2 = a2 + bfc[2];
        float mx = fmaxf(z0, fmaxf(z1, z2));
        float e0 = __expf(z0 - mx), e1 = __expf(z1 - mx), e2 = __expf(z2 - mx);
        float se = e0 + e1 + e2;
        float m  = (float)amask[pos];
        int  lab = labn[pos];
        float zl = (lab == 0) ? z0 : ((lab == 1) ? z1 : z2);
        r0[wv] = (mx + __logf(se) - zl) * m;
        r2[wv] = m;
        float q0 = e0 / se, q1 = e1 / se, q2 = e2 / se;
        alpha[pos] = EPS_C * (q0 * q0 + q1 * q1 + q2 * q2);
#pragma unroll
        for (int cc = 0; cc < 7; ++cc)
            zsp[(size_t)pos * 7 + cc] = z0 * Wtr[cc] + z1 * Wtr[7 + cc] + z2 * Wtr[14 + cc];
    }
    __syncthreads();
    if (threadIdx.x == 0) {
        p0[blockIdx.x] = r0[0] + r0[1] + r0[2] + r0[3];
        p2[blockIdx.x] = r2[0] + r2[1] + r2[2] + r2[3];
    }
}

// ---------------------------------------------------------------------------
// K2: bf16 MFMA GEMM.  C[M,N] = A[M,K] * B[N,K]^T.
//     mode 0: +bias, bf16 out.   mode 1: sigmoid, bf16 out (no bias).
// ---------------------------------------------------------------------------
__global__ __launch_bounds__(256) void gemm_mfma(
    const unsigned short* __restrict__ A, const unsigned short* __restrict__ B,
    const float* __restrict__ bias, void* __restrict__ Cout,
    int M, int N, int K, int mode) {
    __shared__ __align__(16) unsigned short As[128][40];   // +8 pad: conflict-free
    __shared__ __align__(16) unsigned short Bs[128][40];
    const int tid = threadIdx.x;
    const int m0 = blockIdx.y * 128, n0 = blockIdx.x * 128;
    const int wave = tid >> 6, lane = tid & 63;
    const int wm = (wave & 1) * 64, wn = (wave >> 1) * 64;
    const int lm = lane & 15, quad = lane >> 4;
    f32x4 acc[4][4] = {};

    for (int k0 = 0; k0 < K; k0 += 32) {
#pragma unroll
        for (int r = 0; r < 2; ++r) {
            int seg = tid + r * 256;                  // 0..511
            int row = seg >> 2, c16 = (seg & 3) << 3; // 8 bf16 per 16B
            uint4 va = *(const uint4*)(A + (size_t)(m0 + row) * K + k0 + c16);
            *(uint4*)&As[row][c16] = va;
            uint4 vb = *(const uint4*)(B + (size_t)(n0 + row) * K + k0 + c16);
            *(uint4*)&Bs[row][c16] = vb;
        }
        __syncthreads();
        bf16x8 af[4], bfr[4];
#pragma unroll
        for (int i = 0; i < 4; ++i) {
            af[i]  = *(const bf16x8*)&As[wm + i * 16 + lm][quad * 8];
            bfr[i] = *(const bf16x8*)&Bs[wn + i * 16 + lm][quad * 8];
        }
#pragma unroll
        for (int mi = 0; mi < 4; ++mi)
#pragma unroll
            for (int ni = 0; ni < 4; ++ni)
                acc[mi][ni] = __builtin_amdgcn_mfma_f32_16x16x32_bf16(
                    af[mi], bfr[ni], acc[mi][ni], 0, 0, 0);
        __syncthreads();
    }

    const int rbase = quad * 4;
#pragma unroll
    for (int mi = 0; mi < 4; ++mi) {
#pragma unroll
        for (int ni = 0; ni < 4; ++ni) {
            const int col = n0 + wn + ni * 16 + lm;
            const float bv = (mode == 0) ? bias[col] : 0.0f;
#pragma unroll
            for (int r = 0; r < 4; ++r) {
                const int row = m0 + wm + mi * 16 + rbase + r;
                float v = acc[mi][ni][r];
                if (mode == 0)
                    ((unsigned short*)Cout)[(size_t)row * N + col] = f2bf(v + bv);
                else
                    ((unsigned short*)Cout)[(size_t)row * N + col] = f2bf(sigm(v));
            }
        }
    }
}

// ---------------------------------------------------------------------------
// K3: LSTM scan v7 — weight-reuse-across-chains decomposition.
//     256 blocks = 16 chain-groups (4 chains, same dir = same weights)
//                x 16 row-parts (24 h-rows each).
//     Thread (r = gate-row 0..95, p = k-part 0..7): holds 48 fp16 weights
//     (6 uint4 = 24 VGPRs, register-resident) and dots them against 4
//     chains' h -> per-thread weight bytes/step drop 384 -> 96 B (and to 0
//     when resident). v5/v6 were L2-BW-bound at ~39 TB/s on the 288
//     KB/block/step weight stream.
//     Reduction over the 8 k-parts: __shfl_xor butterfly (lanes r*8+p).
//     Exchange: same proven fence-free tag-u64 hx64 scheme; 2 polled
//     loads/thread stage all 4 chains' h (own rows skipped; updaters write
//     them into lh16 directly). One barrier per step, as before.
// ---------------------------------------------------------------------------
#define D16(W, X, A, Bx) { const uint4 xx = (X); \
    A  = dot2acc(__builtin_bit_cast(h2, W.x), __builtin_bit_cast(h2, xx.x), A); \
    Bx = dot2acc(__builtin_bit_cast(h2, W.y), __builtin_bit_cast(h2, xx.y), Bx); \
    A  = dot2acc(__builtin_bit_cast(h2, W.z), __builtin_bit_cast(h2, xx.z), A); \
    Bx = dot2acc(__builtin_bit_cast(h2, W.w), __builtin_bit_cast(h2, xx.w), Bx); }

__global__ __launch_bounds__(768)
__attribute__((amdgpu_waves_per_eu(3, 3)))
void lstm_scan6(
    const unsigned* __restrict__ wpk,          // [2][1536][192] fp16-pairs
    const unsigned short* __restrict__ pre,    // [2][B][S][1536] bf16
    unsigned short* __restrict__ h_sb,         // [S][B][768] bf16
    unsigned long long* __restrict__ hx64) {   // [2][64][384] {tag,val}
    const int blk = blockIdx.x;
    const int grp = blk & 15;                  // chain-group: chains grp*4..grp*4+3
    const int rp  = blk >> 4;                  // row-part: h rows [rp*24, rp*24+24)
    const int d   = grp >> 3;                  // direction (same for whole group)
    const int tid = threadIdx.x;
    const int r   = tid >> 3;                  // gate-row local 0..95 (g*24+u)
    const int p   = tid & 7;                   // k-part 0..7 (48 elems each)
    const int g   = r / 24;
    const int u   = r - g * 24;
    const int G   = g * 384 + rp * 24 + u;     // global gate row (i,f,g,o)

    __shared__ __align__(16) _Float16 lh16[2][4][384];
    __shared__ float    lpreV[384];
    __shared__ unsigned lpreT[384];

    // resident weights: k-slice [p*48, p*48+48) of gate-row G = 6 uint4
    const uint4* wq = (const uint4*)wpk + (size_t)(d * 1536 + G) * 48 + p * 6;
    const uint4 w0 = wq[0], w1 = wq[1], w2 = wq[2],
                w3 = wq[3], w4 = wq[4], w5 = wq[5];

    // lanes p<4 fold pre (chain ci=p) into their accumulator
    const int chp = grp * 4 + (p & 3);
    const unsigned short* prb =
        pre + ((size_t)d * B_SZ + (chp & 31)) * S_LEN * G4 + G;

    float c = 0.0f;

    for (int s = 0; s < S_LEN; ++s) {
        const int t  = d ? (S_LEN - 1 - s) : s;
        const int lb = s & 1;
        float prev = 0.0f;
        if (p < 4) prev = bf2f(prb[(size_t)t * G4]);   // issue early

        // ---- stage h(s-1) for all 4 chains into lh16[lb]
        if (s == 0) {
            if (tid < 384) lpreT[tid] = 0xFFFFFFFFu;
            const int cia = (tid >= 384) ? 1 : 0;
            const int j = tid - cia * 384;
            lh16[0][cia][j]     = (_Float16)0.0f;
            lh16[0][cia + 2][j] = (_Float16)0.0f;
        } else {
            const int cia = (tid >= 384) ? 1 : 0;
            const int j = tid - cia * 384;
            if ((unsigned)(j - rp * 24) >= 24u) {       // own rows: updaters wrote them
                const unsigned long long* sp0 =
                    hx64 + ((size_t)((s - 1) & 1) * 64 + grp * 4 + cia) * 384 + j;
                const unsigned want = (unsigned)(s - 1);
                unsigned long long v0 =
                    __hip_atomic_load(sp0, __ATOMIC_RELAXED, __HIP_MEMORY_SCOPE_AGENT);
                unsigned long long v1 =
                    __hip_atomic_load(sp0 + 768, __ATOMIC_RELAXED, __HIP_MEMORY_SCOPE_AGENT);
                while ((unsigned)(v0 >> 32) != want) {
                    __builtin_amdgcn_s_sleep(1);
                    v0 = __hip_atomic_load(sp0, __ATOMIC_RELAXED, __HIP_MEMORY_SCOPE_AGENT);
                }
                while ((unsigned)(v1 >> 32) != want) {
                    __builtin_amdgcn_s_sleep(1);
                    v1 = __hip_atomic_load(sp0 + 768, __ATOMIC_RELAXED, __HIP_MEMORY_SCOPE_AGENT);
                }
                lh16[lb][cia][j]     = (_Float16)__builtin_bit_cast(float, (unsigned)v0);
                lh16[lb][cia + 2][j] = (_Float16)__builtin_bit_cast(float, (unsigned)v1);
            }
        }
        __syncthreads();                       // the only block-wide barrier

        // ---- dot: 6 uint4 weights vs 4 chains' h (8-way broadcast LDS reads)
        {
            const char* hb = (const char*)&lh16[lb][0][0] + p * 96;
            const uint4* h0 = (const uint4*)(hb);
            const uint4* h1 = (const uint4*)(hb + 768);
            const uint4* h2q = (const uint4*)(hb + 1536);
            const uint4* h3 = (const uint4*)(hb + 2304);
            float a0 = 0.f, a1 = 0.f, a2 = 0.f, a3 = 0.f;
            float b0 = 0.f, b1 = 0.f, b2 = 0.f, b3 = 0.f;
            if      (p == 0) a0 = prev;
            else if (p == 1) a1 = prev;
            else if (p == 2) a2 = prev;
            else if (p == 3) a3 = prev;
            D16(w0, h0[0], a0, b0) D16(w1, h0[1], a0, b0) D16(w2, h0[2], a0, b0)
            D16(w3, h0[3], a0, b0) D16(w4, h0[4], a0, b0) D16(w5, h0[5], a0, b0)
            D16(w0, h1[0], a1, b1) D16(w1, h1[1], a1, b1) D16(w2, h1[2], a1, b1)
            D16(w3, h1[3], a1, b1) D16(w4, h1[4], a1, b1) D16(w5, h1[5], a1, b1)
            D16(w0, h2q[0], a2, b2) D16(w1, h2q[1], a2, b2) D16(w2, h2q[2], a2, b2)
            D16(w3, h2q[3], a2, b2) D16(w4, h2q[4], a2, b2) D16(w5, h2q[5], a2, b2)
            D16(w0, h3[0], a3, b3) D16(w1, h3[1], a3, b3) D16(w2, h3[2], a3, b3)
            D16(w3, h3[3], a3, b3) D16(w4, h3[4], a3, b3) D16(w5, h3[5], a3, b3)
            a0 += b0; a1 += b1; a2 += b2; a3 += b3;
#pragma unroll
            for (int off = 1; off < 8; off <<= 1) {
                a0 += __shfl_xor(a0, off, 64);
                a1 += __shfl_xor(a1, off, 64);
                a2 += __shfl_xor(a2, off, 64);
                a3 += __shfl_xor(a3, off, 64);
            }
            if (p < 4) {
                float av = (p == 0) ? a0 : (p == 1) ? a1 : (p == 2) ? a2 : a3;
                lpreV[p * 96 + r] = av;
                __hip_atomic_store(&lpreT[p * 96 + r], (unsigned)s, __ATOMIC_RELEASE,
                                   __HIP_MEMORY_SCOPE_WORKGROUP);
            }
        }

        // ---- state update (96 owners = 4 chains x 24 rows)
        if (tid < 96) {
            const int ci = tid / 24, uu = tid - ci * 24;
            const unsigned sv = (unsigned)s;
            unsigned* tp = &lpreT[ci * 96 + uu];
#pragma unroll
            for (int jj = 0; jj < 4; ++jj) {
                while (__hip_atomic_load(tp + jj * 24, __ATOMIC_ACQUIRE,
                                         __HIP_MEMORY_SCOPE_WORKGROUP) != sv) {}
            }
            float gi = lpreV[ci * 96 + uu],      gf = lpreV[ci * 96 + 24 + uu];
            float gg = lpreV[ci * 96 + 48 + uu], go = lpreV[ci * 96 + 72 + uu];
            c = sigm(gf) * c + sigm(gi) * tanh_fast(gg);
            float h = sigm(go) * tanh_fast(c);
            const int chain = grp * 4 + ci, bb2 = chain & 31;
            const int rowg = rp * 24 + uu;
            // publish FIRST: inter-block critical path
            unsigned long long v = ((unsigned long long)sv << 32)
                                 | (unsigned long long)__builtin_bit_cast(unsigned, h);
            __hip_atomic_store(hx64 + ((size_t)lb * 64 + chain) * 384 + rowg,
                               v, __ATOMIC_RELAXED, __HIP_MEMORY_SCOPE_AGENT);
            h_sb[((size_t)t * B_SZ + bb2) * HID + d * DH + rowg] = f2bf(h);
            lh16[lb ^ 1][ci][rowg] = (_Float16)h;  // own h for next step
        }
    }
}

// ---------------------------------------------------------------------------
// K5: gated highway recurrence as a parallel chunked linear scan.
//     g bf16, h_s bf16; gscanC runs IN-PLACE on h_sb (bf16 h_tilde out).
// ---------------------------------------------------------------------------
__global__ __launch_bounds__(256) void gscanA(
    const unsigned short* __restrict__ g, const unsigned short* __restrict__ hsb,
    float2* __restrict__ ab) {                 // [NCHK][NCH]
    int id = blockIdx.x * 256 + threadIdx.x;   // < NCHK*NCH
    int chunk = id / NCH, chain = id - chunk * NCH;
    int t0 = chunk * CHK;
    float A = 1.f, Bv = 0.f;
    for (int i = 0; i < CHK; ++i) {
        int t = t0 + i;
        size_t idx = (size_t)t * NCH + chain;
        float gv = bf2f(g[idx]);
        float hv = bf2f(hsb[idx]);
        float a = (t == 0) ? 0.f : (1.f - gv);
        float bb = (t == 0) ? hv : gv * hv;
        A  = a * A;
        Bv = a * Bv + bb;
    }
    ab[id] = make_float2(A, Bv);
}

__global__ __launch_bounds__(256) void gscanB(
    const float2* __restrict__ ab, float* __restrict__ cin) {  // [NCHK][NCH]
    int chain = blockIdx.x * 256 + threadIdx.x;   // < NCH
    float h = 0.f;
#pragma unroll
    for (int j = 0; j < NCHK; ++j) {
        cin[(size_t)j * NCH + chain] = h;
        float2 t = ab[(size_t)j * NCH + chain];
        h = t.x * h + t.y;
    }
}

__global__ __launch_bounds__(256) void gscanC(
    const unsigned short* __restrict__ g, unsigned short* __restrict__ hsb,
    const float* __restrict__ cin) {
    int id = blockIdx.x * 256 + threadIdx.x;
    int chunk = id / NCH, chain = id - chunk * NCH;
    int t0 = chunk * CHK;
    float h = cin[(size_t)chunk * NCH + chain];
    for (int i = 0; i < CHK; ++i) {
        int t = t0 + i;
        size_t idx = (size_t)t * NCH + chain;
        float gv = bf2f(g[idx]);
        float v  = bf2f(hsb[idx]);
        h = (t == 0) ? v : (gv * v + (1.f - gv) * h);
        hsb[idx] = f2bf(h);                    // in-place: h_tilde bf16
    }
}

// ---------------------------------------------------------------------------
// K6: upper head + mix + CE(labels). bf16 h_tilde input. No atomics.
// ---------------------------------------------------------------------------
__global__ __launch_bounds__(256) void final_k(
    const unsigned short* __restrict__ ht, const float* __restrict__ Wup,
    const float* __restrict__ bup, const float* __restrict__ alpha,
    const float* __restrict__ zsp, const int* __restrict__ labels,
    const int* __restrict__ amask, float* __restrict__ out, float* __restrict__ p1) {
    const int gid = blockIdx.x * blockDim.x + threadIdx.x;
    const int pos = gid >> 6, lane = gid & 63, wv = threadIdx.x >> 6;
    __shared__ float r1[4];
    const int bb = pos >> 9, tt = pos & 511;
    const unsigned short* hp = ht + (size_t)tt * (B_SZ * HID) + (size_t)bb * HID;
    float acc[7] = {};
#pragma unroll
    for (int j = 0; j < 12; ++j) {
        int k = lane + (j << 6);
        float hv = bf2f(hp[k]);
        const float* wr = Wup + k * 7;
#pragma unroll
        for (int cc = 0; cc < 7; ++cc) acc[cc] += hv * wr[cc];
    }
#pragma unroll
    for (int cc = 0; cc < 7; ++cc) acc[cc] = wred(acc[cc]);
    if (lane == 0) {
        float al = alpha[pos];
        float z[7], mx = -1e30f;
#pragma unroll
        for (int cc = 0; cc < 7; ++cc) {
            float v = acc[cc] + bup[cc];
            v = zsp[(size_t)pos * 7 + cc] * al + v * (1.0f - al);
            z[cc] = v;
            mx = fmaxf(mx, v);
            out[1 + (size_t)pos * 7 + cc] = v;
        }
        float se = 0.f;
#pragma unroll
        for (int cc = 0; cc < 7; ++cc) se += __expf(z[cc] - mx);
        float lse = mx + __logf(se);
        int lab = labels[pos];
        float zl = z[0];
#pragma unroll
        for (int cc = 1; cc < 7; ++cc) if (lab == cc) zl = z[cc];
        float m = (float)amask[pos];
        r1[wv] = (lse - zl) * m;
    }
    __syncthreads();
    if (threadIdx.x == 0)
        p1[blockIdx.x] = r1[0] + r1[1] + r1[2] + r1[3];
}

// ---------------------------------------------------------------------------
// K7: grid reduction of partials -> d_out[0]. One block, 256 threads.
// ---------------------------------------------------------------------------
__global__ __launch_bounds__(256) void loss_k(
    const float* __restrict__ p0, const float* __restrict__ p1,
    const float* __restrict__ p2, float* __restrict__ out) {
    const int tid = threadIdx.x, lane = tid & 63, wv = tid >> 6;
    __shared__ float rs[4][3];
    float s0 = 0.f, s1 = 0.f, s2 = 0.f;
    for (int i = tid; i < 4096; i += 256) {
        s0 += p0[i]; s1 += p1[i]; s2 += p2[i];
    }
    s0 = wred(s0); s1 = wred(s1); s2 = wred(s2);
    if (lane == 0) { rs[wv][0] = s0; rs[wv][1] = s1; rs[wv][2] = s2; }
    __syncthreads();
    if (tid == 0) {
        float t0 = rs[0][0] + rs[1][0] + rs[2][0] + rs[3][0];
        float t1 = rs[0][1] + rs[1][1] + rs[2][1] + rs[3][1];
        float t2 = rs[0][2] + rs[1][2] + rs[2][2] + rs[3][2];
        out[0] = t0 / t2 + t1 / t2;
    }
}

// ---------------------------------------------------------------------------
extern "C" void kernel_launch(void* const* d_in, const int* in_sizes, int n_in,
                              void* d_out, int out_size, void* d_ws, size_t ws_size,
                              hipStream_t stream) {
    const float* x     = (const float*)d_in[0];
    const int*   amask = (const int*)d_in[1];
    const int*   labels= (const int*)d_in[2];
    const int*   labn  = (const int*)d_in[3];
    const float* Wfc   = (const float*)d_in[4];
    const float* bfc   = (const float*)d_in[5];
    const float* wihf  = (const float*)d_in[6];
    const float* whhf  = (const float*)d_in[7];
    const float* bf    = (const float*)d_in[8];
    const float* wihb  = (const float*)d_in[9];
    const float* whhb  = (const float*)d_in[10];
    const float* bb    = (const float*)d_in[11];
    const float* Wg    = (const float*)d_in[12];
    const float* Wup   = (const float*)d_in[13];
    const float* bup   = (const float*)d_in[14];
    const float* Wtr   = (const float*)d_in[15];
    float* out = (float*)d_out;
    (void)in_sizes; (void)n_in; (void)out_size; (void)ws_size;

    char* ws = (char*)d_ws;
    size_t off = 0;
    auto alloc = [&](size_t bytes) -> char* {
        char* p = ws + off;
        off = (off + bytes + 255) & ~(size_t)255;
        return p;
    };
    unsigned* w16buf    = (unsigned*)alloc((size_t)2 * 1536 * 192 * 4);        // 2.36 MB
    unsigned short* pre = (unsigned short*)alloc((size_t)2 * NPOS * G4 * 2);   // 96 MB
    unsigned short* xb  = (unsigned short*)alloc((size_t)NPOS * HID * 2);      // 24 MB (reused as h_sb)
    unsigned short* wfb = (unsigned short*)alloc((size_t)G4 * HID * 2);        // 2.36 MB
    unsigned short* wbb = (unsigned short*)alloc((size_t)G4 * HID * 2);        // 2.36 MB
    unsigned short* wgt = (unsigned short*)alloc((size_t)HID * HID * 2);       // 1.18 MB
    float* alpha        = (float*)alloc((size_t)NPOS * 4);
    float* zsp          = (float*)alloc((size_t)NPOS * 7 * 4);
    unsigned long long* hx64 = (unsigned long long*)alloc((size_t)2 * 64 * 384 * 8); // 393 KB
    float2* ab          = (float2*)alloc((size_t)NCHK * NCH * 8);              // 1.57 MB
    float* cin          = (float*)alloc((size_t)NCHK * NCH * 4);               // 786 KB
    float* part0        = (float*)alloc(4096 * 4);
    float* part1        = (float*)alloc(4096 * 4);
    float* part2        = (float*)alloc(4096 * 4);
    unsigned short* gbuf = (unsigned short*)pre;  // alias: pre dead after lstm_scan6
    unsigned short* h_sb = xb;                    // alias: xb dead after pre-GEMMs

    // hx64 needs no init: 0xAA poison tag never matches a step tag in [0,512).

    wprep<<<2304, 256, 0, stream>>>(whhf, whhb, w16buf);
    cast_bf16<<<12288, 256, 0, stream>>>(x, xb, NPOS * HID / 4);
    cast_bf16<<<1152, 256, 0, stream>>>(wihf, wfb, G4 * HID / 4);
    cast_bf16<<<1152, 256, 0, stream>>>(wihb, wbb, G4 * HID / 4);
    wgt_prep<<<2304, 256, 0, stream>>>(Wg, wgt);

    zt_kernel<<<4096, 256, 0, stream>>>(x, amask, labn, Wfc, bfc, Wtr, alpha, zsp,
                                        part0, part2);

    // pre = x @ w_ih^T + b  (both directions), bf16 out
    gemm_mfma<<<dim3(12, 128), 256, 0, stream>>>(xb, wfb, bf, pre, NPOS, G4, HID, 0);
    gemm_mfma<<<dim3(12, 128), 256, 0, stream>>>(xb, wbb, bb, pre + (size_t)NPOS * G4,
                                                 NPOS, G4, HID, 0);

    lstm_scan6<<<256, 768, 0, stream>>>(w16buf, pre, h_sb, hx64);

    // g = sigmoid(h_s @ W_gate), bf16 out (gbuf aliases pre)
    gemm_mfma<<<dim3(6, 128), 256, 0, stream>>>(h_sb, wgt, nullptr, gbuf, NPOS, HID, HID, 1);

    // gated highway recurrence: parallel chunked linear scan (bf16, in-place)
    gscanA<<<768, 256, 0, stream>>>(gbuf, h_sb, ab);
    gscanB<<<96, 256, 0, stream>>>(ab, cin);
    gscanC<<<768, 256, 0, stream>>>(gbuf, h_sb, cin);

    final_k<<<4096, 256, 0, stream>>>(h_sb, Wup, bup, alpha, zsp, labels, amask, out, part1);

    loss_k<<<1, 256, 0, stream>>>(part0, part1, part2, out);
}

// Round 3
// 1630.995 us; speedup vs baseline: 1.2434x; 1.2434x over previous
//
#include <hip/hip_runtime.h>

#define B_SZ   32
#define S_LEN  512
#define HID    768
#define DH     384
#define G4     1536
#define NPOS   16384   // B_SZ * S_LEN
#define EPS_C  0.5f
#define NCH    24576   // B_SZ * HID channels
#define CHK    64      // gate-scan chunk length
#define NCHK   8       // S_LEN / CHK

typedef _Float16 h2 __attribute__((ext_vector_type(2)));
typedef short bf16x8 __attribute__((ext_vector_type(8)));
typedef float f32x4 __attribute__((ext_vector_type(4)));

static __device__ __forceinline__ float sigm(float x) { return 1.0f / (1.0f + __expf(-x)); }
static __device__ __forceinline__ float tanh_fast(float x) {
    return 1.0f - 2.0f / (__expf(2.0f * x) + 1.0f);
}

static __device__ __forceinline__ unsigned short f2bf(float f) {
    union { float f; unsigned u; } v; v.f = f;
    unsigned r = v.u + 0x7FFF + ((v.u >> 16) & 1);
    return (unsigned short)(r >> 16);
}
static __device__ __forceinline__ float bf2f(unsigned short u) {
    union { unsigned u; float f; } v; v.u = ((unsigned)u) << 16; return v.f;
}

static __device__ __forceinline__ float wred(float v) {
#pragma unroll
    for (int off = 32; off > 0; off >>= 1) v += __shfl_down(v, off, 64);
    return v;
}

static __device__ __forceinline__ float dot2acc(h2 a, h2 b, float c) {
#if __has_builtin(__builtin_amdgcn_fdot2)
    return __builtin_amdgcn_fdot2(a, b, c, false);
#else
    return c + (float)a.x * (float)b.x + (float)a.y * (float)b.y;
#endif
}

static __device__ __forceinline__ h2 hcast(unsigned u) { return __builtin_bit_cast(h2, u); }

// ---------------------------------------------------------------------------
// K0a: pack w_hh fp32 [1536,384] -> fp16-pair u32 [2][1536][192]  (scan wts)
// ---------------------------------------------------------------------------
__global__ void wprep(const float* __restrict__ wf, const float* __restrict__ wb,
                      unsigned* __restrict__ wpk) {
    int gid = blockIdx.x * 256 + threadIdx.x;       // < 589824
    int d = (gid >= 294912) ? 1 : 0;
    int j = gid - d * 294912;
    const float* src = d ? wb : wf;
    _Float16 a = (_Float16)src[2 * j];
    _Float16 b = (_Float16)src[2 * j + 1];
    unsigned pa = __builtin_bit_cast(unsigned short, a);
    unsigned pb = __builtin_bit_cast(unsigned short, b);
    wpk[(size_t)d * 294912 + j] = pa | (pb << 16);
}

// ---------------------------------------------------------------------------
// K0b: fp32 -> bf16 cast (n multiple of 4)
// ---------------------------------------------------------------------------
__global__ __launch_bounds__(256) void cast_bf16(
    const float* __restrict__ src, unsigned short* __restrict__ dst, int n4) {
    int i = blockIdx.x * 256 + threadIdx.x;
    if (i >= n4) return;
    float4 v = *(const float4*)(src + (size_t)i * 4);
    ushort4 o;
    o.x = f2bf(v.x); o.y = f2bf(v.y); o.z = f2bf(v.z); o.w = f2bf(v.w);
    *(ushort4*)(dst + (size_t)i * 4) = o;
}

// ---------------------------------------------------------------------------
// K0c: W_gate [K=768][N=768] -> bf16 transposed [N][K] (read-coalesced)
// ---------------------------------------------------------------------------
__global__ __launch_bounds__(256) void wgt_prep(
    const float* __restrict__ Wg, unsigned short* __restrict__ Wgt) {
    int i = blockIdx.x * 256 + threadIdx.x;          // < 589824
    int k = i / 768, n = i - k * 768;
    Wgt[(size_t)n * 768 + k] = f2bf(Wg[i]);
}

// ---------------------------------------------------------------------------
// K1: z_t head. One wave / position. NO atomics: per-block partial sums.
// ---------------------------------------------------------------------------
__global__ __launch_bounds__(256) void zt_kernel(
    const float* __restrict__ x, const int* __restrict__ amask,
    const int* __restrict__ labn, const float* __restrict__ Wfc,
    const float* __restrict__ bfc, const float* __restrict__ Wtr,
    float* __restrict__ alpha, float* __restrict__ zsp,
    float* __restrict__ p0, float* __restrict__ p2) {
    const int gid  = blockIdx.x * blockDim.x + threadIdx.x;
    const int pos  = gid >> 6, lane = gid & 63, wv = threadIdx.x >> 6;
    __shared__ float r0[4], r2[4];
    const float* xp = x + (size_t)pos * HID;
    float a0 = 0.f, a1 = 0.f, a2 = 0.f;
#pragma unroll
    for (int j = 0; j < 12; ++j) {
        int k = lane + (j << 6);
        float xv = xp[k];
        a0 += xv * Wfc[k * 3 + 0];
        a1 += xv * Wfc[k * 3 + 1];
        a2 += xv * Wfc[k * 3 + 2];
    }
    a0 = wred(a0); a1 = wred(a1); a2 = wred(a2);
    if (lane == 0) {
        float z0 = a0 + bfc[0], z1 = a1 + bfc[1], z2 = a2 + bfc[2];
        float mx = fmaxf(z0, fmaxf(z1, z2));
        float e0 = __expf(z0 - mx), e1 = __expf(z1 - mx), e2 = __expf(z2 - mx);
        float se = e0 + e1 + e2;
        float m  = (float)amask[pos];
        int  lab = labn[pos];
        float zl = (lab == 0) ? z0 : ((lab == 1) ? z1 : z2);
        r0[wv] = (mx + __logf(se) - zl) * m;
        r2[wv] = m;
        float q0 = e0 / se, q1 = e1 / se, q2 = e2 / se;
        alpha[pos] = EPS_C * (q0 * q0 + q1 * q1 + q2 * q2);
#pragma unroll
        for (int cc = 0; cc < 7; ++cc)
            zsp[(size_t)pos * 7 + cc] = z0 * Wtr[cc] + z1 * Wtr[7 + cc] + z2 * Wtr[14 + cc];
    }
    __syncthreads();
    if (threadIdx.x == 0) {
        p0[blockIdx.x] = r0[0] + r0[1] + r0[2] + r0[3];
        p2[blockIdx.x] = r2[0] + r2[1] + r2[2] + r2[3];
    }
}

// ---------------------------------------------------------------------------
// K2: bf16 MFMA GEMM.  C[M,N] = A[M,K] * B[N,K]^T.
//     mode 0: +bias, bf16 out.   mode 1: sigmoid, bf16 out (no bias).
// ---------------------------------------------------------------------------
__global__ __launch_bounds__(256) void gemm_mfma(
    const unsigned short* __restrict__ A, const unsigned short* __restrict__ B,
    const float* __restrict__ bias, void* __restrict__ Cout,
    int M, int N, int K, int mode) {
    __shared__ __align__(16) unsigned short As[128][40];   // +8 pad: conflict-free
    __shared__ __align__(16) unsigned short Bs[128][40];
    const int tid = threadIdx.x;
    const int m0 = blockIdx.y * 128, n0 = blockIdx.x * 128;
    const int wave = tid >> 6, lane = tid & 63;
    const int wm = (wave & 1) * 64, wn = (wave >> 1) * 64;
    const int lm = lane & 15, quad = lane >> 4;
    f32x4 acc[4][4] = {};

    for (int k0 = 0; k0 < K; k0 += 32) {
#pragma unroll
        for (int r = 0; r < 2; ++r) {
            int seg = tid + r * 256;                  // 0..511
            int row = seg >> 2, c16 = (seg & 3) << 3; // 8 bf16 per 16B
            uint4 va = *(const uint4*)(A + (size_t)(m0 + row) * K + k0 + c16);
            *(uint4*)&As[row][c16] = va;
            uint4 vb = *(const uint4*)(B + (size_t)(n0 + row) * K + k0 + c16);
            *(uint4*)&Bs[row][c16] = vb;
        }
        __syncthreads();
        bf16x8 af[4], bfr[4];
#pragma unroll
        for (int i = 0; i < 4; ++i) {
            af[i]  = *(const bf16x8*)&As[wm + i * 16 + lm][quad * 8];
            bfr[i] = *(const bf16x8*)&Bs[wn + i * 16 + lm][quad * 8];
        }
#pragma unroll
        for (int mi = 0; mi < 4; ++mi)
#pragma unroll
            for (int ni = 0; ni < 4; ++ni)
                acc[mi][ni] = __builtin_amdgcn_mfma_f32_16x16x32_bf16(
                    af[mi], bfr[ni], acc[mi][ni], 0, 0, 0);
        __syncthreads();
    }

    const int rbase = quad * 4;
#pragma unroll
    for (int mi = 0; mi < 4; ++mi) {
#pragma unroll
        for (int ni = 0; ni < 4; ++ni) {
            const int col = n0 + wn + ni * 16 + lm;
            const float bv = (mode == 0) ? bias[col] : 0.0f;
#pragma unroll
            for (int r = 0; r < 4; ++r) {
                const int row = m0 + wm + mi * 16 + rbase + r;
                float v = acc[mi][ni][r];
                if (mode == 0)
                    ((unsigned short*)Cout)[(size_t)row * N + col] = f2bf(v + bv);
                else
                    ((unsigned short*)Cout)[(size_t)row * N + col] = f2bf(sigm(v));
            }
        }
    }
}

// ---------------------------------------------------------------------------
// K3: LSTM scan v7 — fan-in-8 / 48-VGPR-weights middle point.
//     256 blocks = 32 chain-PAIRS (C=2 chains share one weight copy)
//                x 8 row-parts (48 h-rows = 192 gate rows each).
//     Thread (r2 = row-pair 0..95, p = k-part 0..7): holds TWO gate rows'
//     48-elem k-slices (12 uint4 = 48 VGPRs) and dots them against BOTH
//     chains' h-slice (h loaded once, used for 2 rows: LDS reads halved
//     to 12 b128/thread vs v5's 24). amdgpu_waves_per_eu(3,3) forces the
//     exact-3-waves/EU target so the allocator may use ~170 VGPRs (r1's
//     launch_bounds(768,3) is only a MINIMUM and did not raise the cap).
//     Exchange: proven tag-u64 hx64 scheme, ONE polled load per thread;
//     all 8 blocks of a pair on one XCD (blk = rp*32 + q, 32 % 8 == 0).
//     Fan-in 8 (v5: 4 = too few for weight fit; v6: 16 = latency death).
// ---------------------------------------------------------------------------
#define DD(WA, WB, X, SA0, SB0, SA1, SB1) { const uint4 xx = (X); \
    SA0 = dot2acc(hcast(WA.x), hcast(xx.x), SA0); \
    SB0 = dot2acc(hcast(WA.y), hcast(xx.y), SB0); \
    SA0 = dot2acc(hcast(WA.z), hcast(xx.z), SA0); \
    SB0 = dot2acc(hcast(WA.w), hcast(xx.w), SB0); \
    SA1 = dot2acc(hcast(WB.x), hcast(xx.x), SA1); \
    SB1 = dot2acc(hcast(WB.y), hcast(xx.y), SB1); \
    SA1 = dot2acc(hcast(WB.z), hcast(xx.z), SA1); \
    SB1 = dot2acc(hcast(WB.w), hcast(xx.w), SB1); }

__global__ __launch_bounds__(768)
__attribute__((amdgpu_waves_per_eu(3, 3)))
void lstm_scan7(
    const unsigned* __restrict__ wpk,          // [2][1536][192] fp16-pairs
    const unsigned short* __restrict__ pre,    // [2][B][S][1536] bf16
    unsigned short* __restrict__ h_sb,         // [S][B][768] bf16
    unsigned long long* __restrict__ hx64) {   // [2][64][384] {tag,val}
    const int blk = blockIdx.x;
    const int q   = blk & 31;                  // chain pair: chains 2q, 2q+1
    const int rp  = blk >> 5;                  // row-part: h rows [rp*48, rp*48+48)
    const int d   = q >> 4;                    // direction
    const int tid = threadIdx.x;
    const int r2  = tid >> 3;                  // row-pair 0..95 (g*24 + up)
    const int p   = tid & 7;                   // k-part 0..7 (48 elems)
    const int g   = r2 / 24;
    const int up  = r2 - g * 24;
    const int G0  = g * 384 + rp * 48 + up * 2;  // gate row (rowsel 0); +1 = rowsel 1

    __shared__ __align__(16) _Float16 lh16[2][2][384];
    __shared__ float    lpreV[384];
    __shared__ unsigned lpreT[384];

    // resident weights: rows G0, G0+1, k-slice [p*48, p*48+48) = 2 x 6 uint4
    const uint4* wqa = (const uint4*)wpk + (size_t)(d * 1536 + G0) * 48 + p * 6;
    const uint4* wqb = wqa + 48;               // next gate row
    const uint4 wa0 = wqa[0], wa1 = wqa[1], wa2 = wqa[2],
                wa3 = wqa[3], wa4 = wqa[4], wa5 = wqa[5];
    const uint4 wb0 = wqb[0], wb1 = wqb[1], wb2 = wqb[2],
                wb3 = wqb[3], wb4 = wqb[4], wb5 = wqb[5];

    // pre_ih fold: lanes p<4 each own one (chain, rowsel) of the octet's 4 sums
    const int cip = p >> 1, rsel = p & 1;
    const unsigned short* prb =
        pre + ((size_t)d * B_SZ + ((q * 2 + cip) & 31)) * S_LEN * G4 + G0 + rsel;

    // staging role: one u64 per thread (value = chain sci, row sj)
    const int sci = (tid >= 384) ? 1 : 0;
    const int sj  = tid - sci * 384;
    const int sch = q * 2 + sci;
    const bool sown = ((unsigned)(sj - rp * 48) < 48u);

    float c = 0.0f;

    for (int s = 0; s < S_LEN; ++s) {
        const int t  = d ? (S_LEN - 1 - s) : s;
        const int lb = s & 1;
        float prev = 0.0f;
        if (p < 4) prev = bf2f(prb[(size_t)t * G4]);   // issue early

        // ---- stage h(s-1) for both chains into lh16[lb]: 1 poll/thread
        if (s == 0) {
            if (tid < 384) lpreT[tid] = 0xFFFFFFFFu;
            lh16[0][sci][sj] = (_Float16)0.0f;
        } else if (!sown) {
            const unsigned long long* sp =
                hx64 + ((size_t)((s - 1) & 1) * 64 + sch) * 384 + sj;
            const unsigned want = (unsigned)(s - 1);
            unsigned long long v =
                __hip_atomic_load(sp, __ATOMIC_RELAXED, __HIP_MEMORY_SCOPE_AGENT);
            while ((unsigned)(v >> 32) != want) {
                __builtin_amdgcn_s_sleep(1);
                v = __hip_atomic_load(sp, __ATOMIC_RELAXED, __HIP_MEMORY_SCOPE_AGENT);
            }
            lh16[lb][sci][sj] = (_Float16)__builtin_bit_cast(float, (unsigned)v);
        }
        __syncthreads();                       // the only block-wide barrier

        // ---- dot: 12 resident weight uint4 vs 2 chains' h (12 b128 LDS reads)
        {
            const uint4* h0 = (const uint4*)&lh16[lb][0][0] + p * 6;
            const uint4* h1 = (const uint4*)&lh16[lb][1][0] + p * 6;
            float s00a = 0.f, s00b = 0.f, s01a = 0.f, s01b = 0.f;
            float s10a = 0.f, s10b = 0.f, s11a = 0.f, s11b = 0.f;
            if      (p == 0) s00a = prev;      // (chain0,row0)
            else if (p == 1) s01a = prev;      // (chain0,row1)
            else if (p == 2) s10a = prev;      // (chain1,row0)
            else if (p == 3) s11a = prev;      // (chain1,row1)
            DD(wa0, wb0, h0[0], s00a, s00b, s01a, s01b)
            DD(wa1, wb1, h0[1], s00a, s00b, s01a, s01b)
            DD(wa2, wb2, h0[2], s00a, s00b, s01a, s01b)
            DD(wa3, wb3, h0[3], s00a, s00b, s01a, s01b)
            DD(wa4, wb4, h0[4], s00a, s00b, s01a, s01b)
            DD(wa5, wb5, h0[5], s00a, s00b, s01a, s01b)
            DD(wa0, wb0, h1[0], s10a, s10b, s11a, s11b)
            DD(wa1, wb1, h1[1], s10a, s10b, s11a, s11b)
            DD(wa2, wb2, h1[2], s10a, s10b, s11a, s11b)
            DD(wa3, wb3, h1[3], s10a, s10b, s11a, s11b)
            DD(wa4, wb4, h1[4], s10a, s10b, s11a, s11b)
            DD(wa5, wb5, h1[5], s10a, s10b, s11a, s11b)
            float r00 = s00a + s00b, r01 = s01a + s01b;
            float r10 = s10a + s10b, r11 = s11a + s11b;
#pragma unroll
            for (int off = 1; off < 8; off <<= 1) {
                r00 += __shfl_xor(r00, off, 64);
                r01 += __shfl_xor(r01, off, 64);
                r10 += __shfl_xor(r10, off, 64);
                r11 += __shfl_xor(r11, off, 64);
            }
            if (p < 4) {
                float rv = (p == 0) ? r00 : (p == 1) ? r01 : (p == 2) ? r10 : r11;
                const int li = cip * 192 + g * 48 + up * 2 + rsel;
                lpreV[li] = rv;
                __hip_atomic_store(&lpreT[li], (unsigned)s, __ATOMIC_RELEASE,
                                   __HIP_MEMORY_SCOPE_WORKGROUP);
            }
        }

        // ---- state update (96 owners = 2 chains x 48 rows)
        if (tid < 96) {
            const int ci = tid >> 6 ? 1 : (tid >= 48);   // tid/48
            const int urow = tid - ci * 48;
            const int lbase = ci * 192 + urow;
            const unsigned sv = (unsigned)s;
#pragma unroll
            for (int jj = 0; jj < 4; ++jj) {
                while (__hip_atomic_load(&lpreT[lbase + jj * 48], __ATOMIC_ACQUIRE,
                                         __HIP_MEMORY_SCOPE_WORKGROUP) != sv) {}
            }
            float gi = lpreV[lbase],      gf = lpreV[lbase + 48];
            float gg = lpreV[lbase + 96], go = lpreV[lbase + 144];
            c = sigm(gf) * c + sigm(gi) * tanh_fast(gg);
            float h = sigm(go) * tanh_fast(c);
            const int chain = q * 2 + ci, bb2 = chain & 31;
            const int j = rp * 48 + urow;
            // publish FIRST: inter-block critical path
            unsigned long long v = ((unsigned long long)sv << 32)
                                 | (unsigned long long)__builtin_bit_cast(unsigned, h);
            __hip_atomic_store(hx64 + ((size_t)lb * 64 + chain) * 384 + j,
                               v, __ATOMIC_RELAXED, __HIP_MEMORY_SCOPE_AGENT);
            h_sb[((size_t)t * B_SZ + bb2) * HID + d * DH + j] = f2bf(h);
            lh16[lb ^ 1][ci][j] = (_Float16)h;    // own h for next step
        }
    }
}

// ---------------------------------------------------------------------------
// K5: gated highway recurrence as a parallel chunked linear scan.
//     g bf16, h_s bf16; gscanC runs IN-PLACE on h_sb (bf16 h_tilde out).
// ---------------------------------------------------------------------------
__global__ __launch_bounds__(256) void gscanA(
    const unsigned short* __restrict__ g, const unsigned short* __restrict__ hsb,
    float2* __restrict__ ab) {                 // [NCHK][NCH]
    int id = blockIdx.x * 256 + threadIdx.x;   // < NCHK*NCH
    int chunk = id / NCH, chain = id - chunk * NCH;
    int t0 = chunk * CHK;
    float A = 1.f, Bv = 0.f;
    for (int i = 0; i < CHK; ++i) {
        int t = t0 + i;
        size_t idx = (size_t)t * NCH + chain;
        float gv = bf2f(g[idx]);
        float hv = bf2f(hsb[idx]);
        float a = (t == 0) ? 0.f : (1.f - gv);
        float bb = (t == 0) ? hv : gv * hv;
        A  = a * A;
        Bv = a * Bv + bb;
    }
    ab[id] = make_float2(A, Bv);
}

__global__ __launch_bounds__(256) void gscanB(
    const float2* __restrict__ ab, float* __restrict__ cin) {  // [NCHK][NCH]
    int chain = blockIdx.x * 256 + threadIdx.x;   // < NCH
    float h = 0.f;
#pragma unroll
    for (int j = 0; j < NCHK; ++j) {
        cin[(size_t)j * NCH + chain] = h;
        float2 t = ab[(size_t)j * NCH + chain];
        h = t.x * h + t.y;
    }
}

__global__ __launch_bounds__(256) void gscanC(
    const unsigned short* __restrict__ g, unsigned short* __restrict__ hsb,
    const float* __restrict__ cin) {
    int id = blockIdx.x * 256 + threadIdx.x;
    int chunk = id / NCH, chain = id - chunk * NCH;
    int t0 = chunk * CHK;
    float h = cin[(size_t)chunk * NCH + chain];
    for (int i = 0; i < CHK; ++i) {
        int t = t0 + i;
        size_t idx = (size_t)t * NCH + chain;
        float gv = bf2f(g[idx]);
        float v  = bf2f(hsb[idx]);
        h = (t == 0) ? v : (gv * v + (1.f - gv) * h);
        hsb[idx] = f2bf(h);                    // in-place: h_tilde bf16
    }
}

// ---------------------------------------------------------------------------
// K6: upper head + mix + CE(labels). bf16 h_tilde input. No atomics.
// ---------------------------------------------------------------------------
__global__ __launch_bounds__(256) void final_k(
    const unsigned short* __restrict__ ht, const float* __restrict__ Wup,
    const float* __restrict__ bup, const float* __restrict__ alpha,
    const float* __restrict__ zsp, const int* __restrict__ labels,
    const int* __restrict__ amask, float* __restrict__ out, float* __restrict__ p1) {
    const int gid = blockIdx.x * blockDim.x + threadIdx.x;
    const int pos = gid >> 6, lane = gid & 63, wv = threadIdx.x >> 6;
    __shared__ float r1[4];
    const int bb = pos >> 9, tt = pos & 511;
    const unsigned short* hp = ht + (size_t)tt * (B_SZ * HID) + (size_t)bb * HID;
    float acc[7] = {};
#pragma unroll
    for (int j = 0; j < 12; ++j) {
        int k = lane + (j << 6);
        float hv = bf2f(hp[k]);
        const float* wr = Wup + k * 7;
#pragma unroll
        for (int cc = 0; cc < 7; ++cc) acc[cc] += hv * wr[cc];
    }
#pragma unroll
    for (int cc = 0; cc < 7; ++cc) acc[cc] = wred(acc[cc]);
    if (lane == 0) {
        float al = alpha[pos];
        float z[7], mx = -1e30f;
#pragma unroll
        for (int cc = 0; cc < 7; ++cc) {
            float v = acc[cc] + bup[cc];
            v = zsp[(size_t)pos * 7 + cc] * al + v * (1.0f - al);
            z[cc] = v;
            mx = fmaxf(mx, v);
            out[1 + (size_t)pos * 7 + cc] = v;
        }
        float se = 0.f;
#pragma unroll
        for (int cc = 0; cc < 7; ++cc) se += __expf(z[cc] - mx);
        float lse = mx + __logf(se);
        int lab = labels[pos];
        float zl = z[0];
#pragma unroll
        for (int cc = 1; cc < 7; ++cc) if (lab == cc) zl = z[cc];
        float m = (float)amask[pos];
        r1[wv] = (lse - zl) * m;
    }
    __syncthreads();
    if (threadIdx.x == 0)
        p1[blockIdx.x] = r1[0] + r1[1] + r1[2] + r1[3];
}

// ---------------------------------------------------------------------------
// K7: grid reduction of partials -> d_out[0]. One block, 256 threads.
// ---------------------------------------------------------------------------
__global__ __launch_bounds__(256) void loss_k(
    const float* __restrict__ p0, const float* __restrict__ p1,
    const float* __restrict__ p2, float* __restrict__ out) {
    const int tid = threadIdx.x, lane = tid & 63, wv = tid >> 6;
    __shared__ float rs[4][3];
    float s0 = 0.f, s1 = 0.f, s2 = 0.f;
    for (int i = tid; i < 4096; i += 256) {
        s0 += p0[i]; s1 += p1[i]; s2 += p2[i];
    }
    s0 = wred(s0); s1 = wred(s1); s2 = wred(s2);
    if (lane == 0) { rs[wv][0] = s0; rs[wv][1] = s1; rs[wv][2] = s2; }
    __syncthreads();
    if (tid == 0) {
        float t0 = rs[0][0] + rs[1][0] + rs[2][0] + rs[3][0];
        float t1 = rs[0][1] + rs[1][1] + rs[2][1] + rs[3][1];
        float t2 = rs[0][2] + rs[1][2] + rs[2][2] + rs[3][2];
        out[0] = t0 / t2 + t1 / t2;
    }
}

// ---------------------------------------------------------------------------
extern "C" void kernel_launch(void* const* d_in, const int* in_sizes, int n_in,
                              void* d_out, int out_size, void* d_ws, size_t ws_size,
                              hipStream_t stream) {
    const float* x     = (const float*)d_in[0];
    const int*   amask = (const int*)d_in[1];
    const int*   labels= (const int*)d_in[2];
    const int*   labn  = (const int*)d_in[3];
    const float* Wfc   = (const float*)d_in[4];
    const float* bfc   = (const float*)d_in[5];
    const float* wihf  = (const float*)d_in[6];
    const float* whhf  = (const float*)d_in[7];
    const float* bf    = (const float*)d_in[8];
    const float* wihb  = (const float*)d_in[9];
    const float* whhb  = (const float*)d_in[10];
    const float* bb    = (const float*)d_in[11];
    const float* Wg    = (const float*)d_in[12];
    const float* Wup   = (const float*)d_in[13];
    const float* bup   = (const float*)d_in[14];
    const float* Wtr   = (const float*)d_in[15];
    float* out = (float*)d_out;
    (void)in_sizes; (void)n_in; (void)out_size; (void)ws_size;

    char* ws = (char*)d_ws;
    size_t off = 0;
    auto alloc = [&](size_t bytes) -> char* {
        char* p = ws + off;
        off = (off + bytes + 255) & ~(size_t)255;
        return p;
    };
    unsigned* w16buf    = (unsigned*)alloc((size_t)2 * 1536 * 192 * 4);        // 2.36 MB
    unsigned short* pre = (unsigned short*)alloc((size_t)2 * NPOS * G4 * 2);   // 96 MB
    unsigned short* xb  = (unsigned short*)alloc((size_t)NPOS * HID * 2);      // 24 MB (reused as h_sb)
    unsigned short* wfb = (unsigned short*)alloc((size_t)G4 * HID * 2);        // 2.36 MB
    unsigned short* wbb = (unsigned short*)alloc((size_t)G4 * HID * 2);        // 2.36 MB
    unsigned short* wgt = (unsigned short*)alloc((size_t)HID * HID * 2);       // 1.18 MB
    float* alpha        = (float*)alloc((size_t)NPOS * 4);
    float* zsp          = (float*)alloc((size_t)NPOS * 7 * 4);
    unsigned long long* hx64 = (unsigned long long*)alloc((size_t)2 * 64 * 384 * 8); // 393 KB
    float2* ab          = (float2*)alloc((size_t)NCHK * NCH * 8);              // 1.57 MB
    float* cin          = (float*)alloc((size_t)NCHK * NCH * 4);               // 786 KB
    float* part0        = (float*)alloc(4096 * 4);
    float* part1        = (float*)alloc(4096 * 4);
    float* part2        = (float*)alloc(4096 * 4);
    unsigned short* gbuf = (unsigned short*)pre;  // alias: pre dead after lstm_scan7
    unsigned short* h_sb = xb;                    // alias: xb dead after pre-GEMMs

    // hx64 needs no init: 0xAA poison tag never matches a step tag in [0,512).

    wprep<<<2304, 256, 0, stream>>>(whhf, whhb, w16buf);
    cast_bf16<<<12288, 256, 0, stream>>>(x, xb, NPOS * HID / 4);
    cast_bf16<<<1152, 256, 0, stream>>>(wihf, wfb, G4 * HID / 4);
    cast_bf16<<<1152, 256, 0, stream>>>(wihb, wbb, G4 * HID / 4);
    wgt_prep<<<2304, 256, 0, stream>>>(Wg, wgt);

    zt_kernel<<<4096, 256, 0, stream>>>(x, amask, labn, Wfc, bfc, Wtr, alpha, zsp,
                                        part0, part2);

    // pre = x @ w_ih^T + b  (both directions), bf16 out
    gemm_mfma<<<dim3(12, 128), 256, 0, stream>>>(xb, wfb, bf, pre, NPOS, G4, HID, 0);
    gemm_mfma<<<dim3(12, 128), 256, 0, stream>>>(xb, wbb, bb, pre + (size_t)NPOS * G4,
                                                 NPOS, G4, HID, 0);

    lstm_scan7<<<256, 768, 0, stream>>>(w16buf, pre, h_sb, hx64);

    // g = sigmoid(h_s @ W_gate), bf16 out (gbuf aliases pre)
    gemm_mfma<<<dim3(6, 128), 256, 0, stream>>>(h_sb, wgt, nullptr, gbuf, NPOS, HID, HID, 1);

    // gated highway recurrence: parallel chunked linear scan (bf16, in-place)
    gscanA<<<768, 256, 0, stream>>>(gbuf, h_sb, ab);
    gscanB<<<96, 256, 0, stream>>>(ab, cin);
    gscanC<<<768, 256, 0, stream>>>(gbuf, h_sb, cin);

    final_k<<<4096, 256, 0, stream>>>(h_sb, Wup, bup, alpha, zsp, labels, amask, out, part1);

    loss_k<<<1, 256, 0, stream>>>(part0, part1, part2, out);
}

// Round 4
// 1370.843 us; speedup vs baseline: 1.4794x; 1.1898x over previous
//
#include <hip/hip_runtime.h>

#define B_SZ   32
#define S_LEN  512
#define HID    768
#define DH     384
#define G4     1536
#define NPOS   16384   // B_SZ * S_LEN
#define EPS_C  0.5f
#define NCH    24576   // B_SZ * HID channels
#define CHK    64      // gate-scan chunk length
#define NCHK   8       // S_LEN / CHK

typedef _Float16 h2 __attribute__((ext_vector_type(2)));
typedef short bf16x8 __attribute__((ext_vector_type(8)));
typedef float f32x4 __attribute__((ext_vector_type(4)));

static __device__ __forceinline__ float sigm(float x) { return 1.0f / (1.0f + __expf(-x)); }
static __device__ __forceinline__ float tanh_fast(float x) {
    return 1.0f - 2.0f / (__expf(2.0f * x) + 1.0f);
}

static __device__ __forceinline__ unsigned short f2bf(float f) {
    union { float f; unsigned u; } v; v.f = f;
    unsigned r = v.u + 0x7FFF + ((v.u >> 16) & 1);
    return (unsigned short)(r >> 16);
}
static __device__ __forceinline__ float bf2f(unsigned short u) {
    union { unsigned u; float f; } v; v.u = ((unsigned)u) << 16; return v.f;
}

static __device__ __forceinline__ float wred(float v) {
#pragma unroll
    for (int off = 32; off > 0; off >>= 1) v += __shfl_down(v, off, 64);
    return v;
}

static __device__ __forceinline__ float dot2acc(h2 a, h2 b, float c) {
#if __has_builtin(__builtin_amdgcn_fdot2)
    return __builtin_amdgcn_fdot2(a, b, c, false);
#else
    return c + (float)a.x * (float)b.x + (float)a.y * (float)b.y;
#endif
}

static __device__ __forceinline__ h2 hcast(unsigned u) { return __builtin_bit_cast(h2, u); }

// quad-lane reduce step on the VALU (DPP quad_perm), NOT the LDS pipe.
// CTRL 0xB1 = [1,0,3,2] (xor 1), CTRL 0x4E = [2,3,0,1] (xor 2).
template <int CTRL>
static __device__ __forceinline__ float qperm_add(float v) {
#if __has_builtin(__builtin_amdgcn_mov_dpp)
    int o = __builtin_amdgcn_mov_dpp(__builtin_bit_cast(int, v), CTRL, 0xF, 0xF, true);
    return v + __builtin_bit_cast(float, o);
#else
    return v + __shfl_xor(v, (CTRL == 0xB1) ? 1 : 2, 64);
#endif
}

// ---------------------------------------------------------------------------
// K0a: pack w_hh fp32 [1536,384] -> fp16-pair u32 [2][1536][192]  (scan wts)
// ---------------------------------------------------------------------------
__global__ void wprep(const float* __restrict__ wf, const float* __restrict__ wb,
                      unsigned* __restrict__ wpk) {
    int gid = blockIdx.x * 256 + threadIdx.x;       // < 589824
    int d = (gid >= 294912) ? 1 : 0;
    int j = gid - d * 294912;
    const float* src = d ? wb : wf;
    _Float16 a = (_Float16)src[2 * j];
    _Float16 b = (_Float16)src[2 * j + 1];
    unsigned pa = __builtin_bit_cast(unsigned short, a);
    unsigned pb = __builtin_bit_cast(unsigned short, b);
    wpk[(size_t)d * 294912 + j] = pa | (pb << 16);
}

// ---------------------------------------------------------------------------
// K0b: fp32 -> bf16 cast (n multiple of 4)
// ---------------------------------------------------------------------------
__global__ __launch_bounds__(256) void cast_bf16(
    const float* __restrict__ src, unsigned short* __restrict__ dst, int n4) {
    int i = blockIdx.x * 256 + threadIdx.x;
    if (i >= n4) return;
    float4 v = *(const float4*)(src + (size_t)i * 4);
    ushort4 o;
    o.x = f2bf(v.x); o.y = f2bf(v.y); o.z = f2bf(v.z); o.w = f2bf(v.w);
    *(ushort4*)(dst + (size_t)i * 4) = o;
}

// ---------------------------------------------------------------------------
// K0c: W_gate [K=768][N=768] -> bf16 transposed [N][K] (read-coalesced)
// ---------------------------------------------------------------------------
__global__ __launch_bounds__(256) void wgt_prep(
    const float* __restrict__ Wg, unsigned short* __restrict__ Wgt) {
    int i = blockIdx.x * 256 + threadIdx.x;          // < 589824
    int k = i / 768, n = i - k * 768;
    Wgt[(size_t)n * 768 + k] = f2bf(Wg[i]);
}

// ---------------------------------------------------------------------------
// K1: z_t head. One wave / position. NO atomics: per-block partial sums.
// ---------------------------------------------------------------------------
__global__ __launch_bounds__(256) void zt_kernel(
    const float* __restrict__ x, const int* __restrict__ amask,
    const int* __restrict__ labn, const float* __restrict__ Wfc,
    const float* __restrict__ bfc, const float* __restrict__ Wtr,
    float* __restrict__ alpha, float* __restrict__ zsp,
    float* __restrict__ p0, float* __restrict__ p2) {
    const int gid  = blockIdx.x * blockDim.x + threadIdx.x;
    const int pos  = gid >> 6, lane = gid & 63, wv = threadIdx.x >> 6;
    __shared__ float r0[4], r2[4];
    const float* xp = x + (size_t)pos * HID;
    float a0 = 0.f, a1 = 0.f, a2 = 0.f;
#pragma unroll
    for (int j = 0; j < 12; ++j) {
        int k = lane + (j << 6);
        float xv = xp[k];
        a0 += xv * Wfc[k * 3 + 0];
        a1 += xv * Wfc[k * 3 + 1];
        a2 += xv * Wfc[k * 3 + 2];
    }
    a0 = wred(a0); a1 = wred(a1); a2 = wred(a2);
    if (lane == 0) {
        float z0 = a0 + bfc[0], z1 = a1 + bfc[1], z2 = a2 + bfc[2];
        float mx = fmaxf(z0, fmaxf(z1, z2));
        float e0 = __expf(z0 - mx), e1 = __expf(z1 - mx), e2 = __expf(z2 - mx);
        float se = e0 + e1 + e2;
        float m  = (float)amask[pos];
        int  lab = labn[pos];
        float zl = (lab == 0) ? z0 : ((lab == 1) ? z1 : z2);
        r0[wv] = (mx + __logf(se) - zl) * m;
        r2[wv] = m;
        float q0 = e0 / se, q1 = e1 / se, q2 = e2 / se;
        alpha[pos] = EPS_C * (q0 * q0 + q1 * q1 + q2 * q2);
#pragma unroll
        for (int cc = 0; cc < 7; ++cc)
            zsp[(size_t)pos * 7 + cc] = z0 * Wtr[cc] + z1 * Wtr[7 + cc] + z2 * Wtr[14 + cc];
    }
    __syncthreads();
    if (threadIdx.x == 0) {
        p0[blockIdx.x] = r0[0] + r0[1] + r0[2] + r0[3];
        p2[blockIdx.x] = r2[0] + r2[1] + r2[2] + r2[3];
    }
}

// ---------------------------------------------------------------------------
// K2: bf16 MFMA GEMM.  C[M,N] = A[M,K] * B[N,K]^T.
//     mode 0: +bias, bf16 out.   mode 1: sigmoid, bf16 out (no bias).
// ---------------------------------------------------------------------------
__global__ __launch_bounds__(256) void gemm_mfma(
    const unsigned short* __restrict__ A, const unsigned short* __restrict__ B,
    const float* __restrict__ bias, void* __restrict__ Cout,
    int M, int N, int K, int mode) {
    __shared__ __align__(16) unsigned short As[128][40];   // +8 pad: conflict-free
    __shared__ __align__(16) unsigned short Bs[128][40];
    const int tid = threadIdx.x;
    const int m0 = blockIdx.y * 128, n0 = blockIdx.x * 128;
    const int wave = tid >> 6, lane = tid & 63;
    const int wm = (wave & 1) * 64, wn = (wave >> 1) * 64;
    const int lm = lane & 15, quad = lane >> 4;
    f32x4 acc[4][4] = {};

    for (int k0 = 0; k0 < K; k0 += 32) {
#pragma unroll
        for (int r = 0; r < 2; ++r) {
            int seg = tid + r * 256;                  // 0..511
            int row = seg >> 2, c16 = (seg & 3) << 3; // 8 bf16 per 16B
            uint4 va = *(const uint4*)(A + (size_t)(m0 + row) * K + k0 + c16);
            *(uint4*)&As[row][c16] = va;
            uint4 vb = *(const uint4*)(B + (size_t)(n0 + row) * K + k0 + c16);
            *(uint4*)&Bs[row][c16] = vb;
        }
        __syncthreads();
        bf16x8 af[4], bfr[4];
#pragma unroll
        for (int i = 0; i < 4; ++i) {
            af[i]  = *(const bf16x8*)&As[wm + i * 16 + lm][quad * 8];
            bfr[i] = *(const bf16x8*)&Bs[wn + i * 16 + lm][quad * 8];
        }
#pragma unroll
        for (int mi = 0; mi < 4; ++mi)
#pragma unroll
            for (int ni = 0; ni < 4; ++ni)
                acc[mi][ni] = __builtin_amdgcn_mfma_f32_16x16x32_bf16(
                    af[mi], bfr[ni], acc[mi][ni], 0, 0, 0);
        __syncthreads();
    }

    const int rbase = quad * 4;
#pragma unroll
    for (int mi = 0; mi < 4; ++mi) {
#pragma unroll
        for (int ni = 0; ni < 4; ++ni) {
            const int col = n0 + wn + ni * 16 + lm;
            const float bv = (mode == 0) ? bias[col] : 0.0f;
#pragma unroll
            for (int r = 0; r < 4; ++r) {
                const int row = m0 + wm + mi * 16 + rbase + r;
                float v = acc[mi][ni][r];
                if (mode == 0)
                    ((unsigned short*)Cout)[(size_t)row * N + col] = f2bf(v + bv);
                else
                    ((unsigned short*)Cout)[(size_t)row * N + col] = f2bf(sigm(v));
            }
        }
    }
}

// ---------------------------------------------------------------------------
// K3: LSTM scan v8 — v5's proven fan-4 exchange, new dot decomposition.
//     256 blocks = 64 chains x 4 row-parts (UNCHANGED from v5).
//     Thread (j = tid>>2, p = tid&3): gate rows j and j+192 (local), k-quarter
//     p (96 elems). Changes vs v5:
//       * LDS h reads per thread: 24 -> 12 ds_read_b128 (quarter shared by
//         both rows). LDS pipe was ~3900 of v5's 4540 cyc/step.
//       * k-reduce over the 4 quad lanes via DPP quad_perm (VALU) — the
//         __shfl_xor butterflies of v6/v7 were LDS-pipe ops and ate the
//         savings.
//       * weights: row-a 12 uint4 loaded PRE-loop (v7 proved the allocator
//         hoists exactly this much at VGPR=68); row-b 12 uint4 loaded
//         in-loop (L2-hot stream <= 144 KB/block-step, half of v5's).
//         No asm pins (r1: pins force spills).
//     Exchange: identical tag-u64 hx64 scheme, fan-in 4, one barrier/step.
// ---------------------------------------------------------------------------
#define DOT8(W, H, A0, A1) { \
    A0 = dot2acc(hcast(W.x), hcast(H.x), A0); \
    A1 = dot2acc(hcast(W.y), hcast(H.y), A1); \
    A0 = dot2acc(hcast(W.z), hcast(H.z), A0); \
    A1 = dot2acc(hcast(W.w), hcast(H.w), A1); }

__global__ __launch_bounds__(768)
__attribute__((amdgpu_waves_per_eu(3, 3)))
void lstm_scan8(
    const unsigned* __restrict__ wpk,          // [2][1536][192] fp16-pairs
    const unsigned short* __restrict__ pre,    // [2][B][S][1536] bf16
    unsigned short* __restrict__ h_sb,         // [S][B][768] bf16
    unsigned long long* __restrict__ hx64) {   // [2][64][384] {tag,val}
    const int blk   = blockIdx.x;
    const int chain = blk & 63;                // dir*32 + b  (same-XCD spread)
    const int rp    = blk >> 6;                // row-part: h rows [rp*96, +96)
    const int d = chain >> 5, b = chain & 31;
    const int tid = threadIdx.x;
    const int j = tid >> 2;                    // local gate-row pair 0..191
    const int p = tid & 3;                     // k-quarter 0..3 (96 elems)
    const int ga = j / 96, ua = j - ga * 96;
    const int base = rp * 96;
    const int Ga = ga * 384 + base + ua;       // global gate row (pair a)
    // pair b is local row j+192 -> gate ga+2, same u  ->  G = Ga + 768

    __shared__ __align__(16) _Float16 lh16[2][384];
    __shared__ float    lpreV[384];
    __shared__ unsigned lpreT[384];

    // row-a weights: k-quarter p of gate row Ga = 12 uint4 (hoist candidate)
    const uint4* wqA = (const uint4*)wpk + ((size_t)d * 1536 + Ga) * 48 + p * 12;
    const uint4* wqB = wqA + 36864;            // gate row Ga+768
    const uint4 wa0 = wqA[0], wa1 = wqA[1], wa2  = wqA[2],  wa3  = wqA[3],
                wa4 = wqA[4], wa5 = wqA[5], wa6  = wqA[6],  wa7  = wqA[7],
                wa8 = wqA[8], wa9 = wqA[9], wa10 = wqA[10], wa11 = wqA[11];

    // pre_ih fold: lane p==0 carries row a's pre, lane p==1 row b's
    const unsigned short* prb =
        pre + ((size_t)d * B_SZ + b) * S_LEN * G4 + Ga + ((p == 1) ? 768 : 0);

    float c = 0.0f;

    for (int s = 0; s < S_LEN; ++s) {
        const int t  = d ? (S_LEN - 1 - s) : s;
        const int lb = s & 1;
        float prev = 0.0f;
        if (p < 2) prev = bf2f(prb[(size_t)t * G4]);       // issue early
        // row-b streamed weights: issue at loop top, consumed after barrier
        const uint4 xb0 = wqB[0], xb1 = wqB[1], xb2  = wqB[2],  xb3  = wqB[3],
                    xb4 = wqB[4], xb5 = wqB[5], xb6  = wqB[6],  xb7  = wqB[7],
                    xb8 = wqB[8], xb9 = wqB[9], xb10 = wqB[10], xb11 = wqB[11];

        // ---- stage h(s-1) into lh16[lb]: remote 288 via tag-poll (v5 exact)
        if (s == 0) {
            if (tid < 384) { lh16[0][tid] = (_Float16)0.0f; lpreT[tid] = 0xFFFFFFFFu; }
        } else if (tid < 288) {
            const int uu = tid + (tid >= base ? 96 : 0);
            const unsigned long long* srcp =
                hx64 + ((size_t)((s - 1) & 1) * 64 + chain) * 384 + uu;
            unsigned long long v =
                __hip_atomic_load(srcp, __ATOMIC_RELAXED, __HIP_MEMORY_SCOPE_AGENT);
            while ((unsigned)(v >> 32) != (unsigned)(s - 1)) {
                __builtin_amdgcn_s_sleep(1);
                v = __hip_atomic_load(srcp, __ATOMIC_RELAXED, __HIP_MEMORY_SCOPE_AGENT);
            }
            lh16[lb][uu] = (_Float16)__builtin_bit_cast(float, (unsigned)v);
        }
        __syncthreads();                       // the only block-wide barrier

        // ---- dot: 12 LDS b128 reads (h quarter), 2 rows, DPP quad reduce
        {
            const uint4* hq = (const uint4*)&lh16[lb][0] + p * 12;
            const uint4 hv0 = hq[0], hv1 = hq[1], hv2  = hq[2],  hv3  = hq[3],
                        hv4 = hq[4], hv5 = hq[5], hv6  = hq[6],  hv7  = hq[7],
                        hv8 = hq[8], hv9 = hq[9], hv10 = hq[10], hv11 = hq[11];
            float a0 = 0.f, a1 = 0.f, b0 = 0.f, b1 = 0.f;
            DOT8(wa0, hv0, a0, a1)  DOT8(wa1, hv1, a0, a1)  DOT8(wa2,  hv2,  a0, a1)
            DOT8(wa3, hv3, a0, a1)  DOT8(wa4, hv4, a0, a1)  DOT8(wa5,  hv5,  a0, a1)
            DOT8(wa6, hv6, a0, a1)  DOT8(wa7, hv7, a0, a1)  DOT8(wa8,  hv8,  a0, a1)
            DOT8(wa9, hv9, a0, a1)  DOT8(wa10, hv10, a0, a1) DOT8(wa11, hv11, a0, a1)
            DOT8(xb0, hv0, b0, b1)  DOT8(xb1, hv1, b0, b1)  DOT8(xb2,  hv2,  b0, b1)
            DOT8(xb3, hv3, b0, b1)  DOT8(xb4, hv4, b0, b1)  DOT8(xb5,  hv5,  b0, b1)
            DOT8(xb6, hv6, b0, b1)  DOT8(xb7, hv7, b0, b1)  DOT8(xb8,  hv8,  b0, b1)
            DOT8(xb9, hv9, b0, b1)  DOT8(xb10, hv10, b0, b1) DOT8(xb11, hv11, b0, b1)
            float sa = a0 + a1, sb = b0 + b1;
            sa = qperm_add<0xB1>(sa); sa = qperm_add<0x4E>(sa);
            sb = qperm_add<0xB1>(sb); sb = qperm_add<0x4E>(sb);
            if (p == 0) {
                lpreV[j] = sa + prev;
                __hip_atomic_store(&lpreT[j], (unsigned)s, __ATOMIC_RELEASE,
                                   __HIP_MEMORY_SCOPE_WORKGROUP);
            } else if (p == 1) {
                lpreV[j + 192] = sb + prev;
                __hip_atomic_store(&lpreT[j + 192], (unsigned)s, __ATOMIC_RELEASE,
                                   __HIP_MEMORY_SCOPE_WORKGROUP);
            }
        }

        // ---- state update (96 owner threads): poll 4 row tags, then update
        if (tid < 96) {
            const unsigned sv = (unsigned)s;
#pragma unroll
            for (int jj = 0; jj < 4; ++jj) {
                unsigned* tp = &lpreT[jj * 96 + tid];
                while (__hip_atomic_load(tp, __ATOMIC_ACQUIRE,
                                         __HIP_MEMORY_SCOPE_WORKGROUP) != sv) {}
            }
            float gi = lpreV[tid], gf = lpreV[96 + tid];
            float gg = lpreV[192 + tid], go = lpreV[288 + tid];
            c = sigm(gf) * c + sigm(gi) * tanh_fast(gg);
            float h = sigm(go) * tanh_fast(c);
            // publish FIRST: inter-block critical path
            unsigned long long v = ((unsigned long long)sv << 32)
                                 | (unsigned long long)__builtin_bit_cast(unsigned, h);
            __hip_atomic_store(hx64 + ((size_t)lb * 64 + chain) * 384 + base + tid,
                               v, __ATOMIC_RELAXED, __HIP_MEMORY_SCOPE_AGENT);
            h_sb[((size_t)t * B_SZ + b) * HID + d * DH + base + tid] = f2bf(h);
            lh16[lb ^ 1][base + tid] = (_Float16)h;    // own h for next step
        }
    }
}

// ---------------------------------------------------------------------------
// K5: gated highway recurrence as a parallel chunked linear scan.
//     g bf16, h_s bf16; gscanC runs IN-PLACE on h_sb (bf16 h_tilde out).
// ---------------------------------------------------------------------------
__global__ __launch_bounds__(256) void gscanA(
    const unsigned short* __restrict__ g, const unsigned short* __restrict__ hsb,
    float2* __restrict__ ab) {                 // [NCHK][NCH]
    int id = blockIdx.x * 256 + threadIdx.x;   // < NCHK*NCH
    int chunk = id / NCH, chain = id - chunk * NCH;
    int t0 = chunk * CHK;
    float A = 1.f, Bv = 0.f;
    for (int i = 0; i < CHK; ++i) {
        int t = t0 + i;
        size_t idx = (size_t)t * NCH + chain;
        float gv = bf2f(g[idx]);
        float hv = bf2f(hsb[idx]);
        float a = (t == 0) ? 0.f : (1.f - gv);
        float bb = (t == 0) ? hv : gv * hv;
        A  = a * A;
        Bv = a * Bv + bb;
    }
    ab[id] = make_float2(A, Bv);
}

__global__ __launch_bounds__(256) void gscanB(
    const float2* __restrict__ ab, float* __restrict__ cin) {  // [NCHK][NCH]
    int chain = blockIdx.x * 256 + threadIdx.x;   // < NCH
    float h = 0.f;
#pragma unroll
    for (int j = 0; j < NCHK; ++j) {
        cin[(size_t)j * NCH + chain] = h;
        float2 t = ab[(size_t)j * NCH + chain];
        h = t.x * h + t.y;
    }
}

__global__ __launch_bounds__(256) void gscanC(
    const unsigned short* __restrict__ g, unsigned short* __restrict__ hsb,
    const float* __restrict__ cin) {
    int id = blockIdx.x * 256 + threadIdx.x;
    int chunk = id / NCH, chain = id - chunk * NCH;
    int t0 = chunk * CHK;
    float h = cin[(size_t)chunk * NCH + chain];
    for (int i = 0; i < CHK; ++i) {
        int t = t0 + i;
        size_t idx = (size_t)t * NCH + chain;
        float gv = bf2f(g[idx]);
        float v  = bf2f(hsb[idx]);
        h = (t == 0) ? v : (gv * v + (1.f - gv) * h);
        hsb[idx] = f2bf(h);                    // in-place: h_tilde bf16
    }
}

// ---------------------------------------------------------------------------
// K6: upper head + mix + CE(labels). bf16 h_tilde input. No atomics.
// ---------------------------------------------------------------------------
__global__ __launch_bounds__(256) void final_k(
    const unsigned short* __restrict__ ht, const float* __restrict__ Wup,
    const float* __restrict__ bup, const float* __restrict__ alpha,
    const float* __restrict__ zsp, const int* __restrict__ labels,
    const int* __restrict__ amask, float* __restrict__ out, float* __restrict__ p1) {
    const int gid = blockIdx.x * blockDim.x + threadIdx.x;
    const int pos = gid >> 6, lane = gid & 63, wv = threadIdx.x >> 6;
    __shared__ float r1[4];
    const int bb = pos >> 9, tt = pos & 511;
    const unsigned short* hp = ht + (size_t)tt * (B_SZ * HID) + (size_t)bb * HID;
    float acc[7] = {};
#pragma unroll
    for (int j = 0; j < 12; ++j) {
        int k = lane + (j << 6);
        float hv = bf2f(hp[k]);
        const float* wr = Wup + k * 7;
#pragma unroll
        for (int cc = 0; cc < 7; ++cc) acc[cc] += hv * wr[cc];
    }
#pragma unroll
    for (int cc = 0; cc < 7; ++cc) acc[cc] = wred(acc[cc]);
    if (lane == 0) {
        float al = alpha[pos];
        float z[7], mx = -1e30f;
#pragma unroll
        for (int cc = 0; cc < 7; ++cc) {
            float v = acc[cc] + bup[cc];
            v = zsp[(size_t)pos * 7 + cc] * al + v * (1.0f - al);
            z[cc] = v;
            mx = fmaxf(mx, v);
            out[1 + (size_t)pos * 7 + cc] = v;
        }
        float se = 0.f;
#pragma unroll
        for (int cc = 0; cc < 7; ++cc) se += __expf(z[cc] - mx);
        float lse = mx + __logf(se);
        int lab = labels[pos];
        float zl = z[0];
#pragma unroll
        for (int cc = 1; cc < 7; ++cc) if (lab == cc) zl = z[cc];
        float m = (float)amask[pos];
        r1[wv] = (lse - zl) * m;
    }
    __syncthreads();
    if (threadIdx.x == 0)
        p1[blockIdx.x] = r1[0] + r1[1] + r1[2] + r1[3];
}

// ---------------------------------------------------------------------------
// K7: grid reduction of partials -> d_out[0]. One block, 256 threads.
// ---------------------------------------------------------------------------
__global__ __launch_bounds__(256) void loss_k(
    const float* __restrict__ p0, const float* __restrict__ p1,
    const float* __restrict__ p2, float* __restrict__ out) {
    const int tid = threadIdx.x, lane = tid & 63, wv = tid >> 6;
    __shared__ float rs[4][3];
    float s0 = 0.f, s1 = 0.f, s2 = 0.f;
    for (int i = tid; i < 4096; i += 256) {
        s0 += p0[i]; s1 += p1[i]; s2 += p2[i];
    }
    s0 = wred(s0); s1 = wred(s1); s2 = wred(s2);
    if (lane == 0) { rs[wv][0] = s0; rs[wv][1] = s1; rs[wv][2] = s2; }
    __syncthreads();
    if (tid == 0) {
        float t0 = rs[0][0] + rs[1][0] + rs[2][0] + rs[3][0];
        float t1 = rs[0][1] + rs[1][1] + rs[2][1] + rs[3][1];
        float t2 = rs[0][2] + rs[1][2] + rs[2][2] + rs[3][2];
        out[0] = t0 / t2 + t1 / t2;
    }
}

// ---------------------------------------------------------------------------
extern "C" void kernel_launch(void* const* d_in, const int* in_sizes, int n_in,
                              void* d_out, int out_size, void* d_ws, size_t ws_size,
                              hipStream_t stream) {
    const float* x     = (const float*)d_in[0];
    const int*   amask = (const int*)d_in[1];
    const int*   labels= (const int*)d_in[2];
    const int*   labn  = (const int*)d_in[3];
    const float* Wfc   = (const float*)d_in[4];
    const float* bfc   = (const float*)d_in[5];
    const float* wihf  = (const float*)d_in[6];
    const float* whhf  = (const float*)d_in[7];
    const float* bf    = (const float*)d_in[8];
    const float* wihb  = (const float*)d_in[9];
    const float* whhb  = (const float*)d_in[10];
    const float* bb    = (const float*)d_in[11];
    const float* Wg    = (const float*)d_in[12];
    const float* Wup   = (const float*)d_in[13];
    const float* bup   = (const float*)d_in[14];
    const float* Wtr   = (const float*)d_in[15];
    float* out = (float*)d_out;
    (void)in_sizes; (void)n_in; (void)out_size; (void)ws_size;

    char* ws = (char*)d_ws;
    size_t off = 0;
    auto alloc = [&](size_t bytes) -> char* {
        char* p = ws + off;
        off = (off + bytes + 255) & ~(size_t)255;
        return p;
    };
    unsigned* w16buf    = (unsigned*)alloc((size_t)2 * 1536 * 192 * 4);        // 2.36 MB
    unsigned short* pre = (unsigned short*)alloc((size_t)2 * NPOS * G4 * 2);   // 96 MB
    unsigned short* xb  = (unsigned short*)alloc((size_t)NPOS * HID * 2);      // 24 MB (reused as h_sb)
    unsigned short* wfb = (unsigned short*)alloc((size_t)G4 * HID * 2);        // 2.36 MB
    unsigned short* wbb = (unsigned short*)alloc((size_t)G4 * HID * 2);        // 2.36 MB
    unsigned short* wgt = (unsigned short*)alloc((size_t)HID * HID * 2);       // 1.18 MB
    float* alpha        = (float*)alloc((size_t)NPOS * 4);
    float* zsp          = (float*)alloc((size_t)NPOS * 7 * 4);
    unsigned long long* hx64 = (unsigned long long*)alloc((size_t)2 * 64 * 384 * 8); // 393 KB
    float2* ab          = (float2*)alloc((size_t)NCHK * NCH * 8);              // 1.57 MB
    float* cin          = (float*)alloc((size_t)NCHK * NCH * 4);               // 786 KB
    float* part0        = (float*)alloc(4096 * 4);
    float* part1        = (float*)alloc(4096 * 4);
    float* part2        = (float*)alloc(4096 * 4);
    unsigned short* gbuf = (unsigned short*)pre;  // alias: pre dead after lstm_scan8
    unsigned short* h_sb = xb;                    // alias: xb dead after pre-GEMMs

    // hx64 needs no init: 0xAA poison tag never matches a step tag in [0,512).

    wprep<<<2304, 256, 0, stream>>>(whhf, whhb, w16buf);
    cast_bf16<<<12288, 256, 0, stream>>>(x, xb, NPOS * HID / 4);
    cast_bf16<<<1152, 256, 0, stream>>>(wihf, wfb, G4 * HID / 4);
    cast_bf16<<<1152, 256, 0, stream>>>(wihb, wbb, G4 * HID / 4);
    wgt_prep<<<2304, 256, 0, stream>>>(Wg, wgt);

    zt_kernel<<<4096, 256, 0, stream>>>(x, amask, labn, Wfc, bfc, Wtr, alpha, zsp,
                                        part0, part2);

    // pre = x @ w_ih^T + b  (both directions), bf16 out
    gemm_mfma<<<dim3(12, 128), 256, 0, stream>>>(xb, wfb, bf, pre, NPOS, G4, HID, 0);
    gemm_mfma<<<dim3(12, 128), 256, 0, stream>>>(xb, wbb, bb, pre + (size_t)NPOS * G4,
                                                 NPOS, G4, HID, 0);

    lstm_scan8<<<256, 768, 0, stream>>>(w16buf, pre, h_sb, hx64);

    // g = sigmoid(h_s @ W_gate), bf16 out (gbuf aliases pre)
    gemm_mfma<<<dim3(6, 128), 256, 0, stream>>>(h_sb, wgt, nullptr, gbuf, NPOS, HID, HID, 1);

    // gated highway recurrence: parallel chunked linear scan (bf16, in-place)
    gscanA<<<768, 256, 0, stream>>>(gbuf, h_sb, ab);
    gscanB<<<96, 256, 0, stream>>>(ab, cin);
    gscanC<<<768, 256, 0, stream>>>(gbuf, h_sb, cin);

    final_k<<<4096, 256, 0, stream>>>(h_sb, Wup, bup, alpha, zsp, labels, amask, out, part1);

    loss_k<<<1, 256, 0, stream>>>(part0, part1, part2, out);
}

// Round 5
// 1367.953 us; speedup vs baseline: 1.4825x; 1.0021x over previous
//
#include <hip/hip_runtime.h>

#define B_SZ   32
#define S_LEN  512
#define HID    768
#define DH     384
#define G4     1536
#define NPOS   16384   // B_SZ * S_LEN
#define EPS_C  0.5f
#define NCH    24576   // B_SZ * HID channels
#define CHK    64      // gate-scan chunk length
#define NCHK   8       // S_LEN / CHK

typedef _Float16 h2 __attribute__((ext_vector_type(2)));
typedef short bf16x8 __attribute__((ext_vector_type(8)));
typedef float f32x4 __attribute__((ext_vector_type(4)));

static __device__ __forceinline__ float sigm(float x) { return 1.0f / (1.0f + __expf(-x)); }
static __device__ __forceinline__ float tanh_fast(float x) {
    return 1.0f - 2.0f / (__expf(2.0f * x) + 1.0f);
}

static __device__ __forceinline__ unsigned short f2bf(float f) {
    union { float f; unsigned u; } v; v.f = f;
    unsigned r = v.u + 0x7FFF + ((v.u >> 16) & 1);
    return (unsigned short)(r >> 16);
}
static __device__ __forceinline__ float bf2f(unsigned short u) {
    union { unsigned u; float f; } v; v.u = ((unsigned)u) << 16; return v.f;
}

static __device__ __forceinline__ float wred(float v) {
#pragma unroll
    for (int off = 32; off > 0; off >>= 1) v += __shfl_down(v, off, 64);
    return v;
}

static __device__ __forceinline__ float dot2acc(h2 a, h2 b, float c) {
#if __has_builtin(__builtin_amdgcn_fdot2)
    return __builtin_amdgcn_fdot2(a, b, c, false);
#else
    return c + (float)a.x * (float)b.x + (float)a.y * (float)b.y;
#endif
}

static __device__ __forceinline__ h2 hcast(unsigned u) { return __builtin_bit_cast(h2, u); }

// quad-lane reduce step on the VALU (DPP quad_perm), NOT the LDS pipe.
// CTRL 0xB1 = [1,0,3,2] (xor 1), CTRL 0x4E = [2,3,0,1] (xor 2).
template <int CTRL>
static __device__ __forceinline__ float qperm_add(float v) {
#if __has_builtin(__builtin_amdgcn_mov_dpp)
    int o = __builtin_amdgcn_mov_dpp(__builtin_bit_cast(int, v), CTRL, 0xF, 0xF, true);
    return v + __builtin_bit_cast(float, o);
#else
    return v + __shfl_xor(v, (CTRL == 0xB1) ? 1 : 2, 64);
#endif
}

// ---------------------------------------------------------------------------
// K0a: pack w_hh fp32 [1536,384] -> fp16-pair u32 [2][1536][192]  (scan wts)
// ---------------------------------------------------------------------------
__global__ void wprep(const float* __restrict__ wf, const float* __restrict__ wb,
                      unsigned* __restrict__ wpk) {
    int gid = blockIdx.x * 256 + threadIdx.x;       // < 589824
    int d = (gid >= 294912) ? 1 : 0;
    int j = gid - d * 294912;
    const float* src = d ? wb : wf;
    _Float16 a = (_Float16)src[2 * j];
    _Float16 b = (_Float16)src[2 * j + 1];
    unsigned pa = __builtin_bit_cast(unsigned short, a);
    unsigned pb = __builtin_bit_cast(unsigned short, b);
    wpk[(size_t)d * 294912 + j] = pa | (pb << 16);
}

// ---------------------------------------------------------------------------
// K0b: fp32 -> bf16 cast (n multiple of 4)
// ---------------------------------------------------------------------------
__global__ __launch_bounds__(256) void cast_bf16(
    const float* __restrict__ src, unsigned short* __restrict__ dst, int n4) {
    int i = blockIdx.x * 256 + threadIdx.x;
    if (i >= n4) return;
    float4 v = *(const float4*)(src + (size_t)i * 4);
    ushort4 o;
    o.x = f2bf(v.x); o.y = f2bf(v.y); o.z = f2bf(v.z); o.w = f2bf(v.w);
    *(ushort4*)(dst + (size_t)i * 4) = o;
}

// ---------------------------------------------------------------------------
// K0c: W_gate [K=768][N=768] -> bf16 transposed [N][K] (read-coalesced)
// ---------------------------------------------------------------------------
__global__ __launch_bounds__(256) void wgt_prep(
    const float* __restrict__ Wg, unsigned short* __restrict__ Wgt) {
    int i = blockIdx.x * 256 + threadIdx.x;          // < 589824
    int k = i / 768, n = i - k * 768;
    Wgt[(size_t)n * 768 + k] = f2bf(Wg[i]);
}

// ---------------------------------------------------------------------------
// K1: z_t head. One wave / position. NO atomics: per-block partial sums.
// ---------------------------------------------------------------------------
__global__ __launch_bounds__(256) void zt_kernel(
    const float* __restrict__ x, const int* __restrict__ amask,
    const int* __restrict__ labn, const float* __restrict__ Wfc,
    const float* __restrict__ bfc, const float* __restrict__ Wtr,
    float* __restrict__ alpha, float* __restrict__ zsp,
    float* __restrict__ p0, float* __restrict__ p2) {
    const int gid  = blockIdx.x * blockDim.x + threadIdx.x;
    const int pos  = gid >> 6, lane = gid & 63, wv = threadIdx.x >> 6;
    __shared__ float r0[4], r2[4];
    const float* xp = x + (size_t)pos * HID;
    float a0 = 0.f, a1 = 0.f, a2 = 0.f;
#pragma unroll
    for (int j = 0; j < 12; ++j) {
        int k = lane + (j << 6);
        float xv = xp[k];
        a0 += xv * Wfc[k * 3 + 0];
        a1 += xv * Wfc[k * 3 + 1];
        a2 += xv * Wfc[k * 3 + 2];
    }
    a0 = wred(a0); a1 = wred(a1); a2 = wred(a2);
    if (lane == 0) {
        float z0 = a0 + bfc[0], z1 = a1 + bfc[1], z2 = a2 + bfc[2];
        float mx = fmaxf(z0, fmaxf(z1, z2));
        float e0 = __expf(z0 - mx), e1 = __expf(z1 - mx), e2 = __expf(z2 - mx);
        float se = e0 + e1 + e2;
        float m  = (float)amask[pos];
        int  lab = labn[pos];
        float zl = (lab == 0) ? z0 : ((lab == 1) ? z1 : z2);
        r0[wv] = (mx + __logf(se) - zl) * m;
        r2[wv] = m;
        float q0 = e0 / se, q1 = e1 / se, q2 = e2 / se;
        alpha[pos] = EPS_C * (q0 * q0 + q1 * q1 + q2 * q2);
#pragma unroll
        for (int cc = 0; cc < 7; ++cc)
            zsp[(size_t)pos * 7 + cc] = z0 * Wtr[cc] + z1 * Wtr[7 + cc] + z2 * Wtr[14 + cc];
    }
    __syncthreads();
    if (threadIdx.x == 0) {
        p0[blockIdx.x] = r0[0] + r0[1] + r0[2] + r0[3];
        p2[blockIdx.x] = r2[0] + r2[1] + r2[2] + r2[3];
    }
}

// ---------------------------------------------------------------------------
// K2: bf16 MFMA GEMM.  C[M,N] = A[M,K] * B[N,K]^T.
//     mode 0: +bias, bf16 out.   mode 1: sigmoid, bf16 out (no bias).
// ---------------------------------------------------------------------------
__global__ __launch_bounds__(256) void gemm_mfma(
    const unsigned short* __restrict__ A, const unsigned short* __restrict__ B,
    const float* __restrict__ bias, void* __restrict__ Cout,
    int M, int N, int K, int mode) {
    __shared__ __align__(16) unsigned short As[128][40];   // +8 pad: conflict-free
    __shared__ __align__(16) unsigned short Bs[128][40];
    const int tid = threadIdx.x;
    const int m0 = blockIdx.y * 128, n0 = blockIdx.x * 128;
    const int wave = tid >> 6, lane = tid & 63;
    const int wm = (wave & 1) * 64, wn = (wave >> 1) * 64;
    const int lm = lane & 15, quad = lane >> 4;
    f32x4 acc[4][4] = {};

    for (int k0 = 0; k0 < K; k0 += 32) {
#pragma unroll
        for (int r = 0; r < 2; ++r) {
            int seg = tid + r * 256;                  // 0..511
            int row = seg >> 2, c16 = (seg & 3) << 3; // 8 bf16 per 16B
            uint4 va = *(const uint4*)(A + (size_t)(m0 + row) * K + k0 + c16);
            *(uint4*)&As[row][c16] = va;
            uint4 vb = *(const uint4*)(B + (size_t)(n0 + row) * K + k0 + c16);
            *(uint4*)&Bs[row][c16] = vb;
        }
        __syncthreads();
        bf16x8 af[4], bfr[4];
#pragma unroll
        for (int i = 0; i < 4; ++i) {
            af[i]  = *(const bf16x8*)&As[wm + i * 16 + lm][quad * 8];
            bfr[i] = *(const bf16x8*)&Bs[wn + i * 16 + lm][quad * 8];
        }
#pragma unroll
        for (int mi = 0; mi < 4; ++mi)
#pragma unroll
            for (int ni = 0; ni < 4; ++ni)
                acc[mi][ni] = __builtin_amdgcn_mfma_f32_16x16x32_bf16(
                    af[mi], bfr[ni], acc[mi][ni], 0, 0, 0);
        __syncthreads();
    }

    const int rbase = quad * 4;
#pragma unroll
    for (int mi = 0; mi < 4; ++mi) {
#pragma unroll
        for (int ni = 0; ni < 4; ++ni) {
            const int col = n0 + wn + ni * 16 + lm;
            const float bv = (mode == 0) ? bias[col] : 0.0f;
#pragma unroll
            for (int r = 0; r < 4; ++r) {
                const int row = m0 + wm + mi * 16 + rbase + r;
                float v = acc[mi][ni][r];
                if (mode == 0)
                    ((unsigned short*)Cout)[(size_t)row * N + col] = f2bf(v + bv);
                else
                    ((unsigned short*)Cout)[(size_t)row * N + col] = f2bf(sigm(v));
            }
        }
    }
}

// ---------------------------------------------------------------------------
// K3: LSTM scan v9 — v8 structure with BOTH weight rows register-resident.
//     256 blocks = 64 chains x 4 row-parts (v5's proven fan-4 exchange).
//     Thread (j = tid>>2, p = tid&3): gate rows j and j+192 (local),
//     k-quarter p (96 elems). All 24 weight uint4 (96 VGPRs) loaded
//     PRE-loop with waves_per_eu(3,3): v7/v8 proved the allocator keeps
//     pre-loop weight loads resident under this attribute (68/84 VGPR, no
//     spill, no pins). v8's remaining cost was the in-loop row-b stream:
//     its 12 loads shared vmcnt with the exchange's polled atomic loads,
//     so every poll's s_waitcnt also drained the weight stream.
//     LDS: 12 ds_read_b128/thread; k-reduce via DPP quad_perm (VALU pipe).
//     Exchange: identical tag-u64 hx64 scheme, fan-in 4, one barrier/step.
// ---------------------------------------------------------------------------
#define DOT8(W, H, A0, A1) { \
    A0 = dot2acc(hcast(W.x), hcast(H.x), A0); \
    A1 = dot2acc(hcast(W.y), hcast(H.y), A1); \
    A0 = dot2acc(hcast(W.z), hcast(H.z), A0); \
    A1 = dot2acc(hcast(W.w), hcast(H.w), A1); }

__global__ __launch_bounds__(768)
__attribute__((amdgpu_waves_per_eu(3, 3)))
void lstm_scan9(
    const unsigned* __restrict__ wpk,          // [2][1536][192] fp16-pairs
    const unsigned short* __restrict__ pre,    // [2][B][S][1536] bf16
    unsigned short* __restrict__ h_sb,         // [S][B][768] bf16
    unsigned long long* __restrict__ hx64) {   // [2][64][384] {tag,val}
    const int blk   = blockIdx.x;
    const int chain = blk & 63;                // dir*32 + b  (same-XCD spread)
    const int rp    = blk >> 6;                // row-part: h rows [rp*96, +96)
    const int d = chain >> 5, b = chain & 31;
    const int tid = threadIdx.x;
    const int j = tid >> 2;                    // local gate-row pair 0..191
    const int p = tid & 3;                     // k-quarter 0..3 (96 elems)
    const int ga = j / 96, ua = j - ga * 96;
    const int base = rp * 96;
    const int Ga = ga * 384 + base + ua;       // global gate row (pair a)
    // pair b is local row j+192 -> gate ga+2, same u  ->  G = Ga + 768

    __shared__ __align__(16) _Float16 lh16[2][384];
    __shared__ float    lpreV[384];
    __shared__ unsigned lpreT[384];

    // ALL resident weights: k-quarter p of gate rows Ga and Ga+768 = 24 uint4
    const uint4* wqA = (const uint4*)wpk + ((size_t)d * 1536 + Ga) * 48 + p * 12;
    const uint4* wqB = wqA + 36864;            // gate row Ga+768
    const uint4 wa0 = wqA[0], wa1 = wqA[1], wa2  = wqA[2],  wa3  = wqA[3],
                wa4 = wqA[4], wa5 = wqA[5], wa6  = wqA[6],  wa7  = wqA[7],
                wa8 = wqA[8], wa9 = wqA[9], wa10 = wqA[10], wa11 = wqA[11];
    const uint4 wb0 = wqB[0], wb1 = wqB[1], wb2  = wqB[2],  wb3  = wqB[3],
                wb4 = wqB[4], wb5 = wqB[5], wb6  = wqB[6],  wb7  = wqB[7],
                wb8 = wqB[8], wb9 = wqB[9], wb10 = wqB[10], wb11 = wqB[11];

    // pre_ih fold: lane p==0 carries row a's pre, lane p==1 row b's
    const unsigned short* prb =
        pre + ((size_t)d * B_SZ + b) * S_LEN * G4 + Ga + ((p == 1) ? 768 : 0);

    float c = 0.0f;

    for (int s = 0; s < S_LEN; ++s) {
        const int t  = d ? (S_LEN - 1 - s) : s;
        const int lb = s & 1;
        float prev = 0.0f;
        if (p < 2) prev = bf2f(prb[(size_t)t * G4]);       // issue early

        // ---- stage h(s-1) into lh16[lb]: remote 288 via tag-poll (v5 exact)
        if (s == 0) {
            if (tid < 384) { lh16[0][tid] = (_Float16)0.0f; lpreT[tid] = 0xFFFFFFFFu; }
        } else if (tid < 288) {
            const int uu = tid + (tid >= base ? 96 : 0);
            const unsigned long long* srcp =
                hx64 + ((size_t)((s - 1) & 1) * 64 + chain) * 384 + uu;
            unsigned long long v =
                __hip_atomic_load(srcp, __ATOMIC_RELAXED, __HIP_MEMORY_SCOPE_AGENT);
            while ((unsigned)(v >> 32) != (unsigned)(s - 1)) {
                __builtin_amdgcn_s_sleep(1);
                v = __hip_atomic_load(srcp, __ATOMIC_RELAXED, __HIP_MEMORY_SCOPE_AGENT);
            }
            lh16[lb][uu] = (_Float16)__builtin_bit_cast(float, (unsigned)v);
        }
        __syncthreads();                       // the only block-wide barrier

        // ---- dot: 12 LDS b128 reads (h quarter), 2 rows, DPP quad reduce
        {
            const uint4* hq = (const uint4*)&lh16[lb][0] + p * 12;
            const uint4 hv0 = hq[0], hv1 = hq[1], hv2  = hq[2],  hv3  = hq[3],
                        hv4 = hq[4], hv5 = hq[5], hv6  = hq[6],  hv7  = hq[7],
                        hv8 = hq[8], hv9 = hq[9], hv10 = hq[10], hv11 = hq[11];
            float a0 = 0.f, a1 = 0.f, b0 = 0.f, b1 = 0.f;
            DOT8(wa0, hv0, a0, a1)  DOT8(wa1, hv1, a0, a1)  DOT8(wa2,  hv2,  a0, a1)
            DOT8(wa3, hv3, a0, a1)  DOT8(wa4, hv4, a0, a1)  DOT8(wa5,  hv5,  a0, a1)
            DOT8(wa6, hv6, a0, a1)  DOT8(wa7, hv7, a0, a1)  DOT8(wa8,  hv8,  a0, a1)
            DOT8(wa9, hv9, a0, a1)  DOT8(wa10, hv10, a0, a1) DOT8(wa11, hv11, a0, a1)
            DOT8(wb0, hv0, b0, b1)  DOT8(wb1, hv1, b0, b1)  DOT8(wb2,  hv2,  b0, b1)
            DOT8(wb3, hv3, b0, b1)  DOT8(wb4, hv4, b0, b1)  DOT8(wb5,  hv5,  b0, b1)
            DOT8(wb6, hv6, b0, b1)  DOT8(wb7, hv7, b0, b1)  DOT8(wb8,  hv8,  b0, b1)
            DOT8(wb9, hv9, b0, b1)  DOT8(wb10, hv10, b0, b1) DOT8(wb11, hv11, b0, b1)
            float sa = a0 + a1, sb = b0 + b1;
            sa = qperm_add<0xB1>(sa); sa = qperm_add<0x4E>(sa);
            sb = qperm_add<0xB1>(sb); sb = qperm_add<0x4E>(sb);
            if (p == 0) {
                lpreV[j] = sa + prev;
                __hip_atomic_store(&lpreT[j], (unsigned)s, __ATOMIC_RELEASE,
                                   __HIP_MEMORY_SCOPE_WORKGROUP);
            } else if (p == 1) {
                lpreV[j + 192] = sb + prev;
                __hip_atomic_store(&lpreT[j + 192], (unsigned)s, __ATOMIC_RELEASE,
                                   __HIP_MEMORY_SCOPE_WORKGROUP);
            }
        }

        // ---- state update (96 owner threads): poll 4 row tags, then update
        if (tid < 96) {
            const unsigned sv = (unsigned)s;
#pragma unroll
            for (int jj = 0; jj < 4; ++jj) {
                unsigned* tp = &lpreT[jj * 96 + tid];
                while (__hip_atomic_load(tp, __ATOMIC_ACQUIRE,
                                         __HIP_MEMORY_SCOPE_WORKGROUP) != sv) {}
            }
            float gi = lpreV[tid], gf = lpreV[96 + tid];
            float gg = lpreV[192 + tid], go = lpreV[288 + tid];
            c = sigm(gf) * c + sigm(gi) * tanh_fast(gg);
            float h = sigm(go) * tanh_fast(c);
            // publish FIRST: inter-block critical path
            unsigned long long v = ((unsigned long long)sv << 32)
                                 | (unsigned long long)__builtin_bit_cast(unsigned, h);
            __hip_atomic_store(hx64 + ((size_t)lb * 64 + chain) * 384 + base + tid,
                               v, __ATOMIC_RELAXED, __HIP_MEMORY_SCOPE_AGENT);
            h_sb[((size_t)t * B_SZ + b) * HID + d * DH + base + tid] = f2bf(h);
            lh16[lb ^ 1][base + tid] = (_Float16)h;    // own h for next step
        }
    }
}

// ---------------------------------------------------------------------------
// K5: gated highway recurrence as a parallel chunked linear scan.
//     g bf16, h_s bf16; gscanC runs IN-PLACE on h_sb (bf16 h_tilde out).
// ---------------------------------------------------------------------------
__global__ __launch_bounds__(256) void gscanA(
    const unsigned short* __restrict__ g, const unsigned short* __restrict__ hsb,
    float2* __restrict__ ab) {                 // [NCHK][NCH]
    int id = blockIdx.x * 256 + threadIdx.x;   // < NCHK*NCH
    int chunk = id / NCH, chain = id - chunk * NCH;
    int t0 = chunk * CHK;
    float A = 1.f, Bv = 0.f;
    for (int i = 0; i < CHK; ++i) {
        int t = t0 + i;
        size_t idx = (size_t)t * NCH + chain;
        float gv = bf2f(g[idx]);
        float hv = bf2f(hsb[idx]);
        float a = (t == 0) ? 0.f : (1.f - gv);
        float bb = (t == 0) ? hv : gv * hv;
        A  = a * A;
        Bv = a * Bv + bb;
    }
    ab[id] = make_float2(A, Bv);
}

__global__ __launch_bounds__(256) void gscanB(
    const float2* __restrict__ ab, float* __restrict__ cin) {  // [NCHK][NCH]
    int chain = blockIdx.x * 256 + threadIdx.x;   // < NCH
    float h = 0.f;
#pragma unroll
    for (int j = 0; j < NCHK; ++j) {
        cin[(size_t)j * NCH + chain] = h;
        float2 t = ab[(size_t)j * NCH + chain];
        h = t.x * h + t.y;
    }
}

__global__ __launch_bounds__(256) void gscanC(
    const unsigned short* __restrict__ g, unsigned short* __restrict__ hsb,
    const float* __restrict__ cin) {
    int id = blockIdx.x * 256 + threadIdx.x;
    int chunk = id / NCH, chain = id - chunk * NCH;
    int t0 = chunk * CHK;
    float h = cin[(size_t)chunk * NCH + chain];
    for (int i = 0; i < CHK; ++i) {
        int t = t0 + i;
        size_t idx = (size_t)t * NCH + chain;
        float gv = bf2f(g[idx]);
        float v  = bf2f(hsb[idx]);
        h = (t == 0) ? v : (gv * v + (1.f - gv) * h);
        hsb[idx] = f2bf(h);                    // in-place: h_tilde bf16
    }
}

// ---------------------------------------------------------------------------
// K6: upper head + mix + CE(labels). bf16 h_tilde input. No atomics.
// ---------------------------------------------------------------------------
__global__ __launch_bounds__(256) void final_k(
    const unsigned short* __restrict__ ht, const float* __restrict__ Wup,
    const float* __restrict__ bup, const float* __restrict__ alpha,
    const float* __restrict__ zsp, const int* __restrict__ labels,
    const int* __restrict__ amask, float* __restrict__ out, float* __restrict__ p1) {
    const int gid = blockIdx.x * blockDim.x + threadIdx.x;
    const int pos = gid >> 6, lane = gid & 63, wv = threadIdx.x >> 6;
    __shared__ float r1[4];
    const int bb = pos >> 9, tt = pos & 511;
    const unsigned short* hp = ht + (size_t)tt * (B_SZ * HID) + (size_t)bb * HID;
    float acc[7] = {};
#pragma unroll
    for (int j = 0; j < 12; ++j) {
        int k = lane + (j << 6);
        float hv = bf2f(hp[k]);
        const float* wr = Wup + k * 7;
#pragma unroll
        for (int cc = 0; cc < 7; ++cc) acc[cc] += hv * wr[cc];
    }
#pragma unroll
    for (int cc = 0; cc < 7; ++cc) acc[cc] = wred(acc[cc]);
    if (lane == 0) {
        float al = alpha[pos];
        float z[7], mx = -1e30f;
#pragma unroll
        for (int cc = 0; cc < 7; ++cc) {
            float v = acc[cc] + bup[cc];
            v = zsp[(size_t)pos * 7 + cc] * al + v * (1.0f - al);
            z[cc] = v;
            mx = fmaxf(mx, v);
            out[1 + (size_t)pos * 7 + cc] = v;
        }
        float se = 0.f;
#pragma unroll
        for (int cc = 0; cc < 7; ++cc) se += __expf(z[cc] - mx);
        float lse = mx + __logf(se);
        int lab = labels[pos];
        float zl = z[0];
#pragma unroll
        for (int cc = 1; cc < 7; ++cc) if (lab == cc) zl = z[cc];
        float m = (float)amask[pos];
        r1[wv] = (lse - zl) * m;
    }
    __syncthreads();
    if (threadIdx.x == 0)
        p1[blockIdx.x] = r1[0] + r1[1] + r1[2] + r1[3];
}

// ---------------------------------------------------------------------------
// K7: grid reduction of partials -> d_out[0]. One block, 256 threads.
// ---------------------------------------------------------------------------
__global__ __launch_bounds__(256) void loss_k(
    const float* __restrict__ p0, const float* __restrict__ p1,
    const float* __restrict__ p2, float* __restrict__ out) {
    const int tid = threadIdx.x, lane = tid & 63, wv = tid >> 6;
    __shared__ float rs[4][3];
    float s0 = 0.f, s1 = 0.f, s2 = 0.f;
    for (int i = tid; i < 4096; i += 256) {
        s0 += p0[i]; s1 += p1[i]; s2 += p2[i];
    }
    s0 = wred(s0); s1 = wred(s1); s2 = wred(s2);
    if (lane == 0) { rs[wv][0] = s0; rs[wv][1] = s1; rs[wv][2] = s2; }
    __syncthreads();
    if (tid == 0) {
        float t0 = rs[0][0] + rs[1][0] + rs[2][0] + rs[3][0];
        float t1 = rs[0][1] + rs[1][1] + rs[2][1] + rs[3][1];
        float t2 = rs[0][2] + rs[1][2] + rs[2][2] + rs[3][2];
        out[0] = t0 / t2 + t1 / t2;
    }
}

// ---------------------------------------------------------------------------
extern "C" void kernel_launch(void* const* d_in, const int* in_sizes, int n_in,
                              void* d_out, int out_size, void* d_ws, size_t ws_size,
                              hipStream_t stream) {
    const float* x     = (const float*)d_in[0];
    const int*   amask = (const int*)d_in[1];
    const int*   labels= (const int*)d_in[2];
    const int*   labn  = (const int*)d_in[3];
    const float* Wfc   = (const float*)d_in[4];
    const float* bfc   = (const float*)d_in[5];
    const float* wihf  = (const float*)d_in[6];
    const float* whhf  = (const float*)d_in[7];
    const float* bf    = (const float*)d_in[8];
    const float* wihb  = (const float*)d_in[9];
    const float* whhb  = (const float*)d_in[10];
    const float* bb    = (const float*)d_in[11];
    const float* Wg    = (const float*)d_in[12];
    const float* Wup   = (const float*)d_in[13];
    const float* bup   = (const float*)d_in[14];
    const float* Wtr   = (const float*)d_in[15];
    float* out = (float*)d_out;
    (void)in_sizes; (void)n_in; (void)out_size; (void)ws_size;

    char* ws = (char*)d_ws;
    size_t off = 0;
    auto alloc = [&](size_t bytes) -> char* {
        char* p = ws + off;
        off = (off + bytes + 255) & ~(size_t)255;
        return p;
    };
    unsigned* w16buf    = (unsigned*)alloc((size_t)2 * 1536 * 192 * 4);        // 2.36 MB
    unsigned short* pre = (unsigned short*)alloc((size_t)2 * NPOS * G4 * 2);   // 96 MB
    unsigned short* xb  = (unsigned short*)alloc((size_t)NPOS * HID * 2);      // 24 MB (reused as h_sb)
    unsigned short* wfb = (unsigned short*)alloc((size_t)G4 * HID * 2);        // 2.36 MB
    unsigned short* wbb = (unsigned short*)alloc((size_t)G4 * HID * 2);        // 2.36 MB
    unsigned short* wgt = (unsigned short*)alloc((size_t)HID * HID * 2);       // 1.18 MB
    float* alpha        = (float*)alloc((size_t)NPOS * 4);
    float* zsp          = (float*)alloc((size_t)NPOS * 7 * 4);
    unsigned long long* hx64 = (unsigned long long*)alloc((size_t)2 * 64 * 384 * 8); // 393 KB
    float2* ab          = (float2*)alloc((size_t)NCHK * NCH * 8);              // 1.57 MB
    float* cin          = (float*)alloc((size_t)NCHK * NCH * 4);               // 786 KB
    float* part0        = (float*)alloc(4096 * 4);
    float* part1        = (float*)alloc(4096 * 4);
    float* part2        = (float*)alloc(4096 * 4);
    unsigned short* gbuf = (unsigned short*)pre;  // alias: pre dead after lstm_scan9
    unsigned short* h_sb = xb;                    // alias: xb dead after pre-GEMMs

    // hx64 needs no init: 0xAA poison tag never matches a step tag in [0,512).

    wprep<<<2304, 256, 0, stream>>>(whhf, whhb, w16buf);
    cast_bf16<<<12288, 256, 0, stream>>>(x, xb, NPOS * HID / 4);
    cast_bf16<<<1152, 256, 0, stream>>>(wihf, wfb, G4 * HID / 4);
    cast_bf16<<<1152, 256, 0, stream>>>(wihb, wbb, G4 * HID / 4);
    wgt_prep<<<2304, 256, 0, stream>>>(Wg, wgt);

    zt_kernel<<<4096, 256, 0, stream>>>(x, amask, labn, Wfc, bfc, Wtr, alpha, zsp,
                                        part0, part2);

    // pre = x @ w_ih^T + b  (both directions), bf16 out
    gemm_mfma<<<dim3(12, 128), 256, 0, stream>>>(xb, wfb, bf, pre, NPOS, G4, HID, 0);
    gemm_mfma<<<dim3(12, 128), 256, 0, stream>>>(xb, wbb, bb, pre + (size_t)NPOS * G4,
                                                 NPOS, G4, HID, 0);

    lstm_scan9<<<256, 768, 0, stream>>>(w16buf, pre, h_sb, hx64);

    // g = sigmoid(h_s @ W_gate), bf16 out (gbuf aliases pre)
    gemm_mfma<<<dim3(6, 128), 256, 0, stream>>>(h_sb, wgt, nullptr, gbuf, NPOS, HID, HID, 1);

    // gated highway recurrence: parallel chunked linear scan (bf16, in-place)
    gscanA<<<768, 256, 0, stream>>>(gbuf, h_sb, ab);
    gscanB<<<96, 256, 0, stream>>>(ab, cin);
    gscanC<<<768, 256, 0, stream>>>(gbuf, h_sb, cin);

    final_k<<<4096, 256, 0, stream>>>(h_sb, Wup, bup, alpha, zsp, labels, amask, out, part1);

    loss_k<<<1, 256, 0, stream>>>(part0, part1, part2, out);
}